// Round 1
// baseline (1956.938 us; speedup 1.0000x reference)
//
#include <hip/hip_runtime.h>
#include <hip/hip_bf16.h>

#define NN 50000
#define NE 400000
#define NF 128
#define HID 128
#define NH 4
#define HC 32
#define NC 10
#define KHOPS 3

// -------- edge dtype detect: int64 (odd words all zero) vs int32 --------
__global__ void detect_kernel(const int* __restrict__ ei, int* __restrict__ flag) {
    int w = ei[2 * threadIdx.x + 1];
    unsigned long long b = __ballot(w != 0);
    if (threadIdx.x == 0) *flag = (b == 0ULL) ? 1 : 0;  // 1 => int64
}

__device__ __forceinline__ int edge_row(const int* ei, int is64, int e) {
    return is64 ? ei[2 * e] : ei[e];
}
__device__ __forceinline__ int edge_col(const int* ei, int is64, int e) {
    return is64 ? ei[2 * NE + 2 * e] : ei[NE + e];
}

__global__ void zero_kernel(int* __restrict__ p, int n) {
    int i = blockIdx.x * blockDim.x + threadIdx.x;
    if (i < n) p[i] = 0;
}

__global__ void hist_kernel(const int* __restrict__ ei, const int* __restrict__ flag,
                            int* __restrict__ counts) {
    int e = blockIdx.x * blockDim.x + threadIdx.x;
    if (e >= NE) return;
    int c = edge_col(ei, *flag, e);
    atomicAdd(&counts[c], 1);
}

// single-block exclusive scan of counts[NN] -> rowptr[NN+1]; also rewrites
// counts (same buffer reused as scatter cursor) with the exclusive values.
__global__ __launch_bounds__(1024) void scan_kernel(int* __restrict__ counts_cursor,
                                                    int* __restrict__ rowptr) {
    __shared__ int sh[1024];
    __shared__ int running;
    int tid = threadIdx.x;
    if (tid == 0) running = 0;
    __syncthreads();
    for (int base = 0; base < NN; base += 1024) {
        int i = base + tid;
        int v = (i < NN) ? counts_cursor[i] : 0;
        sh[tid] = v;
        __syncthreads();
        for (int off = 1; off < 1024; off <<= 1) {
            int t = (tid >= off) ? sh[tid - off] : 0;
            __syncthreads();
            sh[tid] += t;
            __syncthreads();
        }
        int incl = sh[tid];
        int r0 = running;
        __syncthreads();
        if (i < NN) {
            int ex = r0 + incl - v;
            rowptr[i] = ex;
            counts_cursor[i] = ex;
        }
        if (tid == 1023) running = r0 + incl;
        __syncthreads();
    }
    if (tid == 0) rowptr[NN] = running;
}

__global__ void scatter_kernel(const int* __restrict__ ei, const int* __restrict__ flag,
                               int* __restrict__ cursor, int* __restrict__ srows) {
    int e = blockIdx.x * blockDim.x + threadIdx.x;
    if (e >= NE) return;
    int is64 = *flag;
    int r = edge_row(ei, is64, e);
    int c = edge_col(ei, is64, e);
    int pos = atomicAdd(&cursor[c], 1);
    srows[pos] = r;
}

// -------- x = relu(nf @ Wt + bt) --------
__global__ __launch_bounds__(256) void x_kernel(const float* __restrict__ nf,
                                                const float* __restrict__ Wt,
                                                const float* __restrict__ bt,
                                                float* __restrict__ x) {
    __shared__ float Ws[128 * 128];
    __shared__ float xs[32 * 128];
    __shared__ float bs[128];
    int tid = threadIdx.x;
    int row0 = blockIdx.x * 32;
    for (int i = tid; i < 128 * 128; i += 256) Ws[i] = Wt[i];
    if (tid < 128) bs[tid] = bt[tid];
    for (int i = tid; i < 32 * 128; i += 256) {
        int r = i >> 7, k = i & 127;
        int gr = row0 + r;
        xs[i] = (gr < NN) ? nf[(size_t)gr * 128 + k] : 0.f;
    }
    __syncthreads();
    int c = tid & 127, half = tid >> 7;
    float acc[16];
#pragma unroll
    for (int j = 0; j < 16; j++) acc[j] = bs[c];
    for (int k = 0; k < 128; k++) {
        float w = Ws[k * 128 + c];
#pragma unroll
        for (int j = 0; j < 16; j++) acc[j] += xs[(2 * j + half) * 128 + k] * w;
    }
#pragma unroll
    for (int j = 0; j < 16; j++) {
        int gr = row0 + 2 * j + half;
        if (gr < NN) x[(size_t)gr * 128 + c] = fmaxf(acc[j], 0.f);
    }
}

// -------- per-head Q/K/V: Q=1+elu(x@Wq_h+bq_h), K likewise, V=x@Wv_h+bv_h --------
__global__ __launch_bounds__(256) void qkv_kernel(const float* __restrict__ x,
                                                  const float* __restrict__ Wq, const float* __restrict__ bq,
                                                  const float* __restrict__ Wk, const float* __restrict__ bk,
                                                  const float* __restrict__ Wv, const float* __restrict__ bv,
                                                  int h, float* __restrict__ Qh,
                                                  float* __restrict__ Kh, float* __restrict__ Vh) {
    __shared__ float Wall[128 * 74];
    __shared__ float xs[32 * 128];
    __shared__ float ball[74];
    int tid = threadIdx.x;
    int row0 = blockIdx.x * 32;
    for (int i = tid; i < 128 * 74; i += 256) {
        int k = i / 74, j = i - 74 * k;
        float w;
        if (j < 32) w = Wq[k * 128 + h * 32 + j];
        else if (j < 64) w = Wk[k * 128 + h * 32 + (j - 32)];
        else w = Wv[k * 40 + h * 10 + (j - 64)];
        Wall[i] = w;
    }
    if (tid < 74) {
        float b;
        if (tid < 32) b = bq[h * 32 + tid];
        else if (tid < 64) b = bk[h * 32 + tid - 32];
        else b = bv[h * 10 + tid - 64];
        ball[tid] = b;
    }
    for (int i = tid; i < 32 * 128; i += 256) {
        int r = i >> 7, k = i & 127;
        int gr = row0 + r;
        xs[i] = (gr < NN) ? x[(size_t)gr * 128 + k] : 0.f;
    }
    __syncthreads();
    for (int o = tid; o < 32 * 74; o += 256) {
        int r = o / 74, c = o - 74 * r;
        int gr = row0 + r;
        if (gr >= NN) continue;
        float acc = ball[c];
        const float* xr = &xs[r * 128];
        const float* wc = &Wall[c];
#pragma unroll 8
        for (int k = 0; k < 128; k++) acc += xr[k] * wc[k * 74];
        if (c < 32) Qh[gr * 32 + c] = acc > 0.f ? 1.f + acc : __expf(acc);
        else if (c < 64) Kh[gr * 32 + (c - 32)] = acc > 0.f ? 1.f + acc : __expf(acc);
        else Vh[gr * 10 + (c - 64)] = acc;
    }
}

// -------- out init/accumulate: out[n,c] (+)= hopwise[0] * Vh[n,c] --------
__global__ void vinit_kernel(float* __restrict__ out, const float* __restrict__ Vh,
                             const float* __restrict__ hopwise, int h) {
    int idx = blockIdx.x * blockDim.x + threadIdx.x;
    if (idx >= NN * NC) return;
    float v = hopwise[0] * Vh[idx];
    if (h == 0) out[idx] = v;
    else out[idx] += v;
}

// -------- M0[n,i,c] = Kh[n,i] * Vh[n,c] --------
__global__ void m0_kernel(float* __restrict__ M, const float* __restrict__ Kh,
                          const float* __restrict__ Vh) {
    int idx = blockIdx.x * blockDim.x + threadIdx.x;
    if (idx >= NN * HC * NC) return;
    int n = idx / (HC * NC);
    int t = idx - n * (HC * NC);
    int i = t / NC, c = t - NC * i;
    M[idx] = Kh[n * HC + i] * Vh[n * NC + c];
}

// -------- one hop: Mnext[n] = sum_{e: col=n} Mcur[row_e]; same for K. wave/node --------
__global__ __launch_bounds__(256) void agg_kernel(const float* __restrict__ Mcur,
                                                  const float* __restrict__ Kcur,
                                                  float* __restrict__ Mnext,
                                                  float* __restrict__ Knext,
                                                  const int* __restrict__ rowptr,
                                                  const int* __restrict__ srows) {
    int gw = (blockIdx.x * blockDim.x + threadIdx.x) >> 6;
    int lane = threadIdx.x & 63;
    if (gw >= NN) return;
    int beg = rowptr[gw], end = rowptr[gw + 1];
    float a0 = 0.f, a1 = 0.f, a2 = 0.f, a3 = 0.f, a4 = 0.f, ka = 0.f;
    for (int e = beg; e < end; ++e) {
        int src = srows[e];
        const float* mp = Mcur + (size_t)src * 320 + lane;
        a0 += mp[0];
        a1 += mp[64];
        a2 += mp[128];
        a3 += mp[192];
        a4 += mp[256];
        if (lane < 32) ka += Kcur[src * 32 + lane];
    }
    float* o = Mnext + (size_t)gw * 320 + lane;
    o[0] = a0; o[64] = a1; o[128] = a2; o[192] = a3; o[256] = a4;
    if (lane < 32) Knext[gw * 32 + lane] = ka;
}

// -------- H = (Q.M)/(Q.K + CST); out += gamma * H --------
__global__ void h_kernel(float* __restrict__ out, const float* __restrict__ Q,
                         const float* __restrict__ M, const float* __restrict__ Kf,
                         const float* __restrict__ hopwise, const float* __restrict__ headwise,
                         int h, int hop) {
    int idx = blockIdx.x * blockDim.x + threadIdx.x;
    if (idx >= NN * NC) return;
    int n = idx / NC, c = idx - n * NC;
    float e0 = __expf(headwise[0 * KHOPS + hop]);
    float e1 = __expf(headwise[1 * KHOPS + hop]);
    float e2 = __expf(headwise[2 * KHOPS + hop]);
    float e3 = __expf(headwise[3 * KHOPS + hop]);
    float esum = e0 + e1 + e2 + e3;
    float eh = (h == 0) ? e0 : (h == 1) ? e1 : (h == 2) ? e2 : e3;
    float gamma = hopwise[hop + 1] * eh / esum;
    const float* q = Q + n * HC;
    const float* m = M + (size_t)n * (HC * NC) + c;
    const float* k = Kf + n * HC;
    float num = 0.f, den = 1e-5f;
#pragma unroll
    for (int i = 0; i < HC; i++) {
        float qi = q[i];
        num += qi * m[i * NC];
        den += qi * k[i];
    }
    out[idx] += gamma * num / den;
}

extern "C" void kernel_launch(void* const* d_in, const int* in_sizes, int n_in,
                              void* d_out, int out_size, void* d_ws, size_t ws_size,
                              hipStream_t stream) {
    const float* nf = (const float*)d_in[0];
    const int* ei = (const int*)d_in[1];
    const float* Wt = (const float*)d_in[2];
    const float* bt = (const float*)d_in[3];
    const float* Wq = (const float*)d_in[4];
    const float* bq = (const float*)d_in[5];
    const float* Wk = (const float*)d_in[6];
    const float* bk = (const float*)d_in[7];
    const float* Wv = (const float*)d_in[8];
    const float* bv = (const float*)d_in[9];
    const float* hopwise = (const float*)d_in[10];
    const float* headwise = (const float*)d_in[11];
    float* out = (float*)d_out;

    char* p = (char*)d_ws;
    auto alloc = [&](size_t bytes) {
        char* r = p;
        p += (bytes + 255) & ~(size_t)255;
        return r;
    };
    int* rowptr = (int*)alloc((NN + 1) * sizeof(int));
    int* cursor = (int*)alloc((NN + 1) * sizeof(int));
    int* srows = (int*)alloc((size_t)NE * sizeof(int));
    int* flag = (int*)alloc(sizeof(int));
    float* x = (float*)alloc((size_t)NN * HID * sizeof(float));
    float* Qh = (float*)alloc((size_t)NN * HC * sizeof(float));
    float* Ka = (float*)alloc((size_t)NN * HC * sizeof(float));
    float* Kb = (float*)alloc((size_t)NN * HC * sizeof(float));
    float* Vh = (float*)alloc((size_t)NN * NC * sizeof(float));
    float* Ma = (float*)alloc((size_t)NN * HC * NC * sizeof(float));
    float* Mb = (float*)alloc((size_t)NN * HC * NC * sizeof(float));

    detect_kernel<<<1, 64, 0, stream>>>(ei, flag);
    zero_kernel<<<(NN + 255) / 256, 256, 0, stream>>>(cursor, NN);
    hist_kernel<<<(NE + 255) / 256, 256, 0, stream>>>(ei, flag, cursor);
    scan_kernel<<<1, 1024, 0, stream>>>(cursor, rowptr);
    scatter_kernel<<<(NE + 255) / 256, 256, 0, stream>>>(ei, flag, cursor, srows);

    x_kernel<<<(NN + 31) / 32, 256, 0, stream>>>(nf, Wt, bt, x);

    for (int h = 0; h < NH; h++) {
        qkv_kernel<<<(NN + 31) / 32, 256, 0, stream>>>(x, Wq, bq, Wk, bk, Wv, bv, h, Qh, Ka, Vh);
        vinit_kernel<<<(NN * NC + 255) / 256, 256, 0, stream>>>(out, Vh, hopwise, h);
        m0_kernel<<<(NN * HC * NC + 255) / 256, 256, 0, stream>>>(Ma, Ka, Vh);
        float* Mc = Ma; float* Mn = Mb; float* Kc = Ka; float* Kn = Kb;
        for (int hop = 0; hop < KHOPS; hop++) {
            agg_kernel<<<(NN + 3) / 4, 256, 0, stream>>>(Mc, Kc, Mn, Kn, rowptr, srows);
            h_kernel<<<(NN * NC + 255) / 256, 256, 0, stream>>>(out, Qh, Mn, Kn, hopwise, headwise, h, hop);
            float* t = Mc; Mc = Mn; Mn = t;
            t = Kc; Kc = Kn; Kn = t;
        }
    }
}

// Round 2
// 946.515 us; speedup vs baseline: 2.0675x; 2.0675x over previous
//
#include <hip/hip_runtime.h>
#include <hip/hip_bf16.h>

#define NN 50000
#define NE 400000
#define NF 128
#define HID 128
#define NH 4
#define HC 32
#define NC 10
#define KHOPS 3

typedef unsigned int uint;
typedef unsigned short ushort;

// -------- edge dtype detect: int64 (odd words all zero) vs int32 --------
__global__ void detect_kernel(const int* __restrict__ ei, int* __restrict__ flag) {
    int w = ei[2 * threadIdx.x + 1];
    unsigned long long b = __ballot(w != 0);
    if (threadIdx.x == 0) *flag = (b == 0ULL) ? 1 : 0;  // 1 => int64
}

__device__ __forceinline__ int edge_row(const int* ei, int is64, int e) {
    return is64 ? ei[2 * e] : ei[e];
}
__device__ __forceinline__ int edge_col(const int* ei, int is64, int e) {
    return is64 ? ei[2 * NE + 2 * e] : ei[NE + e];
}

__global__ void zero_kernel(int* __restrict__ p, int n) {
    int i = blockIdx.x * blockDim.x + threadIdx.x;
    if (i < n) p[i] = 0;
}

__global__ void hist_kernel(const int* __restrict__ ei, const int* __restrict__ flag,
                            int* __restrict__ counts) {
    int e = blockIdx.x * blockDim.x + threadIdx.x;
    if (e >= NE) return;
    int c = edge_col(ei, *flag, e);
    atomicAdd(&counts[c], 1);
}

__global__ __launch_bounds__(1024) void scan_kernel(int* __restrict__ counts_cursor,
                                                    int* __restrict__ rowptr) {
    __shared__ int sh[1024];
    __shared__ int running;
    int tid = threadIdx.x;
    if (tid == 0) running = 0;
    __syncthreads();
    for (int base = 0; base < NN; base += 1024) {
        int i = base + tid;
        int v = (i < NN) ? counts_cursor[i] : 0;
        sh[tid] = v;
        __syncthreads();
        for (int off = 1; off < 1024; off <<= 1) {
            int t = (tid >= off) ? sh[tid - off] : 0;
            __syncthreads();
            sh[tid] += t;
            __syncthreads();
        }
        int incl = sh[tid];
        int r0 = running;
        __syncthreads();
        if (i < NN) {
            int ex = r0 + incl - v;
            rowptr[i] = ex;
            counts_cursor[i] = ex;
        }
        if (tid == 1023) running = r0 + incl;
        __syncthreads();
    }
    if (tid == 0) rowptr[NN] = running;
}

__global__ void scatter_kernel(const int* __restrict__ ei, const int* __restrict__ flag,
                               int* __restrict__ cursor, int* __restrict__ srows) {
    int e = blockIdx.x * blockDim.x + threadIdx.x;
    if (e >= NE) return;
    int is64 = *flag;
    int r = edge_row(ei, is64, e);
    int c = edge_col(ei, is64, e);
    int pos = atomicAdd(&cursor[c], 1);
    srows[pos] = r;
}

// ======== k-tiled f32 GEMM kernels (64 rows/block, register-blocked) ========

// stage 64 rows x 32 k of src into xs[32][68] (transposed, padded)
__device__ __forceinline__ void stage_x(float xs[32][68], const float* __restrict__ src,
                                        int row0, int kt, int tid) {
#pragma unroll
    for (int v = 0; v < 2; v++) {
        int idx = v * 256 + tid;      // 0..511
        int r = idx >> 3;             // 0..63
        int kq = idx & 7;             // float4 chunk within 32-k tile
        int gr = row0 + r;
        float4 f = {0.f, 0.f, 0.f, 0.f};
        if (gr < NN) f = *(const float4*)(src + (size_t)gr * 128 + kt * 32 + kq * 4);
        xs[kq * 4 + 0][r] = f.x;
        xs[kq * 4 + 1][r] = f.y;
        xs[kq * 4 + 2][r] = f.z;
        xs[kq * 4 + 3][r] = f.w;
    }
}

// -------- x = relu(nf @ Wt + bt) : 64x128 tile / block --------
__global__ __launch_bounds__(256) void x_kernel(const float* __restrict__ nf,
                                                const float* __restrict__ Wt,
                                                const float* __restrict__ bt,
                                                float* __restrict__ x) {
    __shared__ float ws[32][128];
    __shared__ float xs[32][68];
    int tid = threadIdx.x;
    int row0 = blockIdx.x * 64;
    int tx = tid & 31;   // col group: c0 = tx*4
    int ty = tid >> 5;   // row group: r0 = ty*8
    int c0 = tx * 4, r0 = ty * 8;
    float acc[8][4];
#pragma unroll
    for (int rr = 0; rr < 8; rr++)
#pragma unroll
        for (int cc = 0; cc < 4; cc++) acc[rr][cc] = bt[c0 + cc];

    for (int kt = 0; kt < 4; kt++) {
        // stage W tile [32][128]
#pragma unroll
        for (int v = 0; v < 4; v++) {
            int e = v * 1024 + tid * 4;
            *(float4*)&ws[0][e] = *(const float4*)(Wt + kt * 32 * 128 + e);
        }
        stage_x(xs, nf, row0, kt, tid);
        __syncthreads();
#pragma unroll
        for (int kk = 0; kk < 32; kk++) {
            float4 w = *(const float4*)&ws[kk][c0];
            float4 xa = *(const float4*)&xs[kk][r0];
            float4 xb = *(const float4*)&xs[kk][r0 + 4];
            float xv[8] = {xa.x, xa.y, xa.z, xa.w, xb.x, xb.y, xb.z, xb.w};
            float wv[4] = {w.x, w.y, w.z, w.w};
#pragma unroll
            for (int rr = 0; rr < 8; rr++)
#pragma unroll
                for (int cc = 0; cc < 4; cc++) acc[rr][cc] += xv[rr] * wv[cc];
        }
        __syncthreads();
    }
#pragma unroll
    for (int rr = 0; rr < 8; rr++) {
        int gr = row0 + r0 + rr;
        if (gr >= NN) continue;
        float4 o = {fmaxf(acc[rr][0], 0.f), fmaxf(acc[rr][1], 0.f),
                    fmaxf(acc[rr][2], 0.f), fmaxf(acc[rr][3], 0.f)};
        *(float4*)(x + (size_t)gr * 128 + c0) = o;
    }
}

// -------- QK for all heads: cols 0-127 = Q, 128-255 = K; 1+elu applied --------
// Qall/Kall layout: [h][n][32]
__global__ __launch_bounds__(256) void qk_kernel(const float* __restrict__ x,
                                                 const float* __restrict__ Wq, const float* __restrict__ bq,
                                                 const float* __restrict__ Wk, const float* __restrict__ bk,
                                                 float* __restrict__ Qall, float* __restrict__ Kall) {
    __shared__ float ws[32][256];
    __shared__ float xs[32][68];
    int tid = threadIdx.x;
    int row0 = blockIdx.x * 64;
    int tx = tid & 31;   // c0 = tx*8
    int ty = tid >> 5;   // r0 = ty*8
    int c0 = tx * 8, r0 = ty * 8;
    float acc[8][8];
#pragma unroll
    for (int cc = 0; cc < 8; cc++) {
        int c = c0 + cc;
        float b = (c < 128) ? bq[c] : bk[c - 128];
#pragma unroll
        for (int rr = 0; rr < 8; rr++) acc[rr][cc] = b;
    }
    for (int kt = 0; kt < 4; kt++) {
#pragma unroll
        for (int v = 0; v < 8; v++) {
            int e = v * 1024 + tid * 4;   // 0..8191
            int k = e >> 8, c = e & 255;
            float4 f;
            if (c < 128) f = *(const float4*)(Wq + (kt * 32 + k) * 128 + c);
            else f = *(const float4*)(Wk + (kt * 32 + k) * 128 + (c - 128));
            *(float4*)&ws[k][c] = f;
        }
        stage_x(xs, x, row0, kt, tid);
        __syncthreads();
#pragma unroll
        for (int kk = 0; kk < 32; kk++) {
            float4 w0 = *(const float4*)&ws[kk][c0];
            float4 w1 = *(const float4*)&ws[kk][c0 + 4];
            float4 xa = *(const float4*)&xs[kk][r0];
            float4 xb = *(const float4*)&xs[kk][r0 + 4];
            float xv[8] = {xa.x, xa.y, xa.z, xa.w, xb.x, xb.y, xb.z, xb.w};
            float wv[8] = {w0.x, w0.y, w0.z, w0.w, w1.x, w1.y, w1.z, w1.w};
#pragma unroll
            for (int rr = 0; rr < 8; rr++)
#pragma unroll
                for (int cc = 0; cc < 8; cc++) acc[rr][cc] += xv[rr] * wv[cc];
        }
        __syncthreads();
    }
#pragma unroll
    for (int rr = 0; rr < 8; rr++) {
        int gr = row0 + r0 + rr;
        if (gr >= NN) continue;
        float vals[8];
#pragma unroll
        for (int cc = 0; cc < 8; cc++) {
            float z = acc[rr][cc];
            vals[cc] = z > 0.f ? 1.f + z : __expf(z);
        }
        float* base;
        if (c0 < 128) {
            int hh = c0 >> 5, ii = c0 & 31;
            base = Qall + (size_t)hh * NN * 32 + (size_t)gr * 32 + ii;
        } else {
            int hh = (c0 - 128) >> 5, ii = (c0 - 128) & 31;
            base = Kall + (size_t)hh * NN * 32 + (size_t)gr * 32 + ii;
        }
        *(float4*)base = {vals[0], vals[1], vals[2], vals[3]};
        *(float4*)(base + 4) = {vals[4], vals[5], vals[6], vals[7]};
    }
}

// -------- V for all heads: Vall[n][40] = x @ Wv + bv (no activation) --------
__global__ __launch_bounds__(256) void v_kernel(const float* __restrict__ x,
                                                const float* __restrict__ Wv, const float* __restrict__ bv,
                                                float* __restrict__ Vall) {
    __shared__ float ws[32][40];
    __shared__ float xs[32][68];
    int tid = threadIdx.x;
    int row0 = blockIdx.x * 64;
    int cg = tid & 7;    // c0 = cg*5
    int rg = tid >> 3;   // r0 = rg*2
    int c0 = cg * 5, r0 = rg * 2;
    float acc[2][5];
#pragma unroll
    for (int cc = 0; cc < 5; cc++) {
        float b = bv[c0 + cc];
        acc[0][cc] = b;
        acc[1][cc] = b;
    }
    for (int kt = 0; kt < 4; kt++) {
        for (int e = tid; e < 1280; e += 256) {
            int k = e / 40, c = e - 40 * k;
            ws[k][c] = Wv[(kt * 32 + k) * 40 + c];
        }
        stage_x(xs, x, row0, kt, tid);
        __syncthreads();
#pragma unroll
        for (int kk = 0; kk < 32; kk++) {
            float x0 = xs[kk][r0], x1 = xs[kk][r0 + 1];
#pragma unroll
            for (int cc = 0; cc < 5; cc++) {
                float w = ws[kk][c0 + cc];
                acc[0][cc] += x0 * w;
                acc[1][cc] += x1 * w;
            }
        }
        __syncthreads();
    }
#pragma unroll
    for (int rr = 0; rr < 2; rr++) {
        int gr = row0 + r0 + rr;
        if (gr >= NN) continue;
#pragma unroll
        for (int cc = 0; cc < 5; cc++) Vall[(size_t)gr * 40 + c0 + cc] = acc[rr][cc];
    }
}

// -------- out[n,c] = hopwise[0] * sum_h Vall[n][h*10+c] --------
__global__ void vinit_kernel(float* __restrict__ out, const float* __restrict__ Vall,
                             const float* __restrict__ hopwise) {
    int idx = blockIdx.x * blockDim.x + threadIdx.x;
    if (idx >= NN * NC) return;
    int n = idx / NC, c = idx - n * NC;
    const float* v = Vall + (size_t)n * 40 + c;
    out[idx] = hopwise[0] * (v[0] + v[10] + v[20] + v[30]);
}

// -------- M0 (bf16) + K0 (bf16) for head h --------
__device__ __forceinline__ uint packbf(float a, float b) {
    __hip_bfloat162 t = __float22bfloat162_rn(float2{a, b});
    return *reinterpret_cast<uint*>(&t);
}
__device__ __forceinline__ float bflo(uint u) { return __uint_as_float(u << 16); }
__device__ __forceinline__ float bfhi(uint u) { return __uint_as_float(u & 0xFFFF0000u); }

__global__ void m0_kernel(uint* __restrict__ Mbf, ushort* __restrict__ Kbf,
                          const float* __restrict__ Kall, const float* __restrict__ Vall, int h) {
    int gid = blockIdx.x * blockDim.x + threadIdx.x;
    if (gid >= NN * HC) return;
    int n = gid >> 5, i = gid & 31;
    float kv = Kall[(size_t)h * NN * 32 + (size_t)n * 32 + i];
    __hip_bfloat16 kb = __float2bfloat16(kv);
    Kbf[(size_t)n * 32 + i] = *reinterpret_cast<ushort*>(&kb);
    const float* v = Vall + (size_t)n * 40 + h * 10;
    uint* mp = Mbf + (size_t)n * 160 + i * 5;
#pragma unroll
    for (int t = 0; t < 5; t++) mp[t] = packbf(kv * v[2 * t], kv * v[2 * t + 1]);
}

// -------- fused hop: aggregate (bf16) + H readout + out accumulation --------
// wave per dst node; lanes = [2 edges in flight] x [32 i-lanes]
__global__ __launch_bounds__(256) void agg_kernel(const uint* __restrict__ Mcur,
                                                  const ushort* __restrict__ Kcur,
                                                  const float* __restrict__ Qall,
                                                  float* __restrict__ out,
                                                  uint* __restrict__ Mnext,
                                                  ushort* __restrict__ Knext,
                                                  const int* __restrict__ rowptr,
                                                  const int* __restrict__ srows,
                                                  const float* __restrict__ hopwise,
                                                  const float* __restrict__ headwise,
                                                  int h, int hop, int write_next) {
    int gw = (blockIdx.x * 256 + threadIdx.x) >> 6;   // node (uniform per wave)
    int lane = threadIdx.x & 63;
    int half = lane >> 5, i = lane & 31;
    int beg = rowptr[gw], end = rowptr[gw + 1];
    float acc[10] = {0.f, 0.f, 0.f, 0.f, 0.f, 0.f, 0.f, 0.f, 0.f, 0.f};
    float kacc = 0.f;
    for (int e = beg + half; e < end; e += 2) {
        int src = srows[e];
        const uint* mp = Mcur + (size_t)src * 160 + i * 5;
        uint u0 = mp[0], u1 = mp[1], u2 = mp[2], u3 = mp[3], u4 = mp[4];
        kacc += __uint_as_float(((uint)Kcur[(size_t)src * 32 + i]) << 16);
        acc[0] += bflo(u0); acc[1] += bfhi(u0);
        acc[2] += bflo(u1); acc[3] += bfhi(u1);
        acc[4] += bflo(u2); acc[5] += bfhi(u2);
        acc[6] += bflo(u3); acc[7] += bfhi(u3);
        acc[8] += bflo(u4); acc[9] += bfhi(u4);
    }
    // fold the two edge-halves
#pragma unroll
    for (int c = 0; c < 10; c++) acc[c] += __shfl_xor(acc[c], 32);
    kacc += __shfl_xor(kacc, 32);

    // H readout: num[c] = sum_i Q[n,i]*M[n,i,c]; den = sum_i Q[n,i]*Kf[n,i]
    float q = Qall[(size_t)h * NN * 32 + (size_t)gw * 32 + i];
    float num[10];
#pragma unroll
    for (int c = 0; c < 10; c++) num[c] = q * acc[c];
    float den = q * kacc;
#pragma unroll
    for (int off = 16; off >= 1; off >>= 1) {
#pragma unroll
        for (int c = 0; c < 10; c++) num[c] += __shfl_xor(num[c], off);
        den += __shfl_xor(den, off);
    }
    float e0 = __expf(headwise[0 * KHOPS + hop]);
    float e1 = __expf(headwise[1 * KHOPS + hop]);
    float e2 = __expf(headwise[2 * KHOPS + hop]);
    float e3 = __expf(headwise[3 * KHOPS + hop]);
    float eh = (h == 0) ? e0 : (h == 1) ? e1 : (h == 2) ? e2 : e3;
    float gamma = hopwise[hop + 1] * eh / (e0 + e1 + e2 + e3);
    float scale = gamma / (den + 1e-5f);
    if (lane < 10) {
        float v = lane == 0 ? num[0] : lane == 1 ? num[1] : lane == 2 ? num[2] :
                  lane == 3 ? num[3] : lane == 4 ? num[4] : lane == 5 ? num[5] :
                  lane == 6 ? num[6] : lane == 7 ? num[7] : lane == 8 ? num[8] : num[9];
        out[(size_t)gw * 10 + lane] += v * scale;
    }
    if (write_next && half == 0) {
        uint* op = Mnext + (size_t)gw * 160 + i * 5;
        op[0] = packbf(acc[0], acc[1]);
        op[1] = packbf(acc[2], acc[3]);
        op[2] = packbf(acc[4], acc[5]);
        op[3] = packbf(acc[6], acc[7]);
        op[4] = packbf(acc[8], acc[9]);
        __hip_bfloat16 kb = __float2bfloat16(kacc);
        Knext[(size_t)gw * 32 + i] = *reinterpret_cast<ushort*>(&kb);
    }
}

extern "C" void kernel_launch(void* const* d_in, const int* in_sizes, int n_in,
                              void* d_out, int out_size, void* d_ws, size_t ws_size,
                              hipStream_t stream) {
    const float* nf = (const float*)d_in[0];
    const int* ei = (const int*)d_in[1];
    const float* Wt = (const float*)d_in[2];
    const float* bt = (const float*)d_in[3];
    const float* Wq = (const float*)d_in[4];
    const float* bq = (const float*)d_in[5];
    const float* Wk = (const float*)d_in[6];
    const float* bk = (const float*)d_in[7];
    const float* Wv = (const float*)d_in[8];
    const float* bv = (const float*)d_in[9];
    const float* hopwise = (const float*)d_in[10];
    const float* headwise = (const float*)d_in[11];
    float* out = (float*)d_out;

    char* p = (char*)d_ws;
    auto alloc = [&](size_t bytes) {
        char* r = p;
        p += (bytes + 255) & ~(size_t)255;
        return r;
    };
    int* rowptr = (int*)alloc((NN + 1) * sizeof(int));
    int* cursor = (int*)alloc((NN + 1) * sizeof(int));
    int* srows = (int*)alloc((size_t)NE * sizeof(int));
    int* flag = (int*)alloc(sizeof(int));
    float* x = (float*)alloc((size_t)NN * HID * sizeof(float));
    float* Qall = (float*)alloc((size_t)NH * NN * HC * sizeof(float));
    float* Kall = (float*)alloc((size_t)NH * NN * HC * sizeof(float));
    float* Vall = (float*)alloc((size_t)NN * 40 * sizeof(float));
    uint* Ma = (uint*)alloc((size_t)NN * 160 * sizeof(uint));
    uint* Mb = (uint*)alloc((size_t)NN * 160 * sizeof(uint));
    ushort* Ka = (ushort*)alloc((size_t)NN * 32 * sizeof(ushort));
    ushort* Kb = (ushort*)alloc((size_t)NN * 32 * sizeof(ushort));

    detect_kernel<<<1, 64, 0, stream>>>(ei, flag);
    zero_kernel<<<(NN + 255) / 256, 256, 0, stream>>>(cursor, NN);
    hist_kernel<<<(NE + 255) / 256, 256, 0, stream>>>(ei, flag, cursor);
    scan_kernel<<<1, 1024, 0, stream>>>(cursor, rowptr);
    scatter_kernel<<<(NE + 255) / 256, 256, 0, stream>>>(ei, flag, cursor, srows);

    int nrb = (NN + 63) / 64;
    x_kernel<<<nrb, 256, 0, stream>>>(nf, Wt, bt, x);
    qk_kernel<<<nrb, 256, 0, stream>>>(x, Wq, bq, Wk, bk, Qall, Kall);
    v_kernel<<<nrb, 256, 0, stream>>>(x, Wv, bv, Vall);
    vinit_kernel<<<(NN * NC + 255) / 256, 256, 0, stream>>>(out, Vall, hopwise);

    for (int h = 0; h < NH; h++) {
        m0_kernel<<<(NN * HC + 255) / 256, 256, 0, stream>>>(Ma, Ka, Kall, Vall, h);
        uint* Mc = Ma; uint* Mn = Mb;
        ushort* Kc = Ka; ushort* Kn = Kb;
        for (int hop = 0; hop < KHOPS; hop++) {
            agg_kernel<<<NN / 4, 256, 0, stream>>>(Mc, Kc, Qall, out, Mn, Kn,
                                                   rowptr, srows, hopwise, headwise,
                                                   h, hop, hop < KHOPS - 1 ? 1 : 0);
            uint* t = Mc; Mc = Mn; Mn = t;
            ushort* tk = Kc; Kc = Kn; Kn = tk;
        }
    }
}

// Round 3
// 762.496 us; speedup vs baseline: 2.5665x; 1.2413x over previous
//
#include <hip/hip_runtime.h>
#include <hip/hip_bf16.h>

#define NN 50000
#define NE 400000
#define NF 128
#define HID 128
#define NH 4
#define HC 32
#define NC 10
#define KHOPS 3
#define NBLK ((NN + 1023) / 1024)   // 49

typedef unsigned int uint;
typedef unsigned short ushort;

// -------- edge dtype detect: int64 (odd words all zero) vs int32 --------
__global__ void detect_kernel(const int* __restrict__ ei, int* __restrict__ flag) {
    int w = ei[2 * threadIdx.x + 1];
    unsigned long long b = __ballot(w != 0);
    if (threadIdx.x == 0) *flag = (b == 0ULL) ? 1 : 0;  // 1 => int64
}

__device__ __forceinline__ int edge_row(const int* ei, int is64, int e) {
    return is64 ? ei[2 * e] : ei[e];
}
__device__ __forceinline__ int edge_col(const int* ei, int is64, int e) {
    return is64 ? ei[2 * NE + 2 * e] : ei[NE + e];
}

__global__ void zero_kernel(int* __restrict__ p, int n) {
    int i = blockIdx.x * blockDim.x + threadIdx.x;
    if (i < n) p[i] = 0;
}

__global__ void hist_kernel(const int* __restrict__ ei, const int* __restrict__ flag,
                            int* __restrict__ counts) {
    int e = blockIdx.x * blockDim.x + threadIdx.x;
    if (e >= NE) return;
    int c = edge_col(ei, *flag, e);
    atomicAdd(&counts[c], 1);
}

// ---- hierarchical scan: A) per-block sums B) scan block sums C) re-scan+offset ----
__global__ __launch_bounds__(256) void bsum_kernel(const int* __restrict__ counts,
                                                   int* __restrict__ bsum) {
    int b = blockIdx.x, tid = threadIdx.x;
    int base = b * 1024 + tid * 4;
    int4 v = {0, 0, 0, 0};
    if (base < NN) v = *(const int4*)(counts + base);
    int s = v.x + v.y + v.z + v.w;
#pragma unroll
    for (int off = 32; off >= 1; off >>= 1) s += __shfl_xor(s, off);
    __shared__ int ws[4];
    int lane = tid & 63, w = tid >> 6;
    if (lane == 0) ws[w] = s;
    __syncthreads();
    if (tid == 0) bsum[b] = ws[0] + ws[1] + ws[2] + ws[3];
}

__global__ void bscan_kernel(const int* __restrict__ bsum, int* __restrict__ boff,
                             int* __restrict__ rowptr) {
    int lane = threadIdx.x;
    int v = (lane < NBLK) ? bsum[lane] : 0;
    int t = v;
#pragma unroll
    for (int off = 1; off < 64; off <<= 1) {
        int u = __shfl_up(t, off);
        if (lane >= off) t += u;
    }
    if (lane < NBLK) boff[lane] = t - v;
    if (lane == NBLK - 1) rowptr[NN] = t;
}

__global__ __launch_bounds__(256) void scanb_kernel(const int* __restrict__ counts,
                                                    const int* __restrict__ boff,
                                                    int* __restrict__ rowptr,
                                                    int* __restrict__ cursor) {
    int b = blockIdx.x, tid = threadIdx.x;
    int base = b * 1024 + tid * 4;
    int4 v = {0, 0, 0, 0};
    if (base < NN) v = *(const int4*)(counts + base);
    int s3 = v.x + v.y + v.z + v.w;
    int lane = tid & 63, w = tid >> 6;
    int t = s3;
#pragma unroll
    for (int off = 1; off < 64; off <<= 1) {
        int u = __shfl_up(t, off);
        if (lane >= off) t += u;
    }
    __shared__ int ws[4];
    if (lane == 63) ws[w] = t;
    __syncthreads();
    int wofs = boff[b];
    for (int i = 0; i < 4; i++) wofs += (i < w) ? ws[i] : 0;
    int excl = wofs + t - s3;
    if (base < NN) {
        int4 o;
        o.x = excl;
        o.y = excl + v.x;
        o.z = o.y + v.y;
        o.w = o.z + v.z;
        *(int4*)(rowptr + base) = o;
        *(int4*)(cursor + base) = o;
    }
}

__global__ void scatter_kernel(const int* __restrict__ ei, const int* __restrict__ flag,
                               int* __restrict__ cursor, int* __restrict__ srows) {
    int e = blockIdx.x * blockDim.x + threadIdx.x;
    if (e >= NE) return;
    int is64 = *flag;
    int r = edge_row(ei, is64, e);
    int c = edge_col(ei, is64, e);
    int pos = atomicAdd(&cursor[c], 1);
    srows[pos] = r;
}

// ======== k-tiled f32 GEMM kernels (64 rows/block, register-blocked) ========

__device__ __forceinline__ void stage_x(float xs[32][68], const float* __restrict__ src,
                                        int row0, int kt, int tid) {
#pragma unroll
    for (int v = 0; v < 2; v++) {
        int idx = v * 256 + tid;
        int r = idx >> 3;
        int kq = idx & 7;
        int gr = row0 + r;
        float4 f = {0.f, 0.f, 0.f, 0.f};
        if (gr < NN) f = *(const float4*)(src + (size_t)gr * 128 + kt * 32 + kq * 4);
        xs[kq * 4 + 0][r] = f.x;
        xs[kq * 4 + 1][r] = f.y;
        xs[kq * 4 + 2][r] = f.z;
        xs[kq * 4 + 3][r] = f.w;
    }
}

__global__ __launch_bounds__(256) void x_kernel(const float* __restrict__ nf,
                                                const float* __restrict__ Wt,
                                                const float* __restrict__ bt,
                                                float* __restrict__ x) {
    __shared__ float ws[32][128];
    __shared__ float xs[32][68];
    int tid = threadIdx.x;
    int row0 = blockIdx.x * 64;
    int tx = tid & 31, ty = tid >> 5;
    int c0 = tx * 4, r0 = ty * 8;
    float acc[8][4];
#pragma unroll
    for (int rr = 0; rr < 8; rr++)
#pragma unroll
        for (int cc = 0; cc < 4; cc++) acc[rr][cc] = bt[c0 + cc];

    for (int kt = 0; kt < 4; kt++) {
#pragma unroll
        for (int v = 0; v < 4; v++) {
            int e = v * 1024 + tid * 4;
            *(float4*)&ws[0][e] = *(const float4*)(Wt + kt * 32 * 128 + e);
        }
        stage_x(xs, nf, row0, kt, tid);
        __syncthreads();
#pragma unroll
        for (int kk = 0; kk < 32; kk++) {
            float4 w = *(const float4*)&ws[kk][c0];
            float4 xa = *(const float4*)&xs[kk][r0];
            float4 xb = *(const float4*)&xs[kk][r0 + 4];
            float xv[8] = {xa.x, xa.y, xa.z, xa.w, xb.x, xb.y, xb.z, xb.w};
            float wv[4] = {w.x, w.y, w.z, w.w};
#pragma unroll
            for (int rr = 0; rr < 8; rr++)
#pragma unroll
                for (int cc = 0; cc < 4; cc++) acc[rr][cc] += xv[rr] * wv[cc];
        }
        __syncthreads();
    }
#pragma unroll
    for (int rr = 0; rr < 8; rr++) {
        int gr = row0 + r0 + rr;
        if (gr >= NN) continue;
        float4 o = {fmaxf(acc[rr][0], 0.f), fmaxf(acc[rr][1], 0.f),
                    fmaxf(acc[rr][2], 0.f), fmaxf(acc[rr][3], 0.f)};
        *(float4*)(x + (size_t)gr * 128 + c0) = o;
    }
}

__global__ __launch_bounds__(256) void qk_kernel(const float* __restrict__ x,
                                                 const float* __restrict__ Wq, const float* __restrict__ bq,
                                                 const float* __restrict__ Wk, const float* __restrict__ bk,
                                                 float* __restrict__ Qall, float* __restrict__ Kall) {
    __shared__ float ws[32][256];
    __shared__ float xs[32][68];
    int tid = threadIdx.x;
    int row0 = blockIdx.x * 64;
    int tx = tid & 31, ty = tid >> 5;
    int c0 = tx * 8, r0 = ty * 8;
    float acc[8][8];
#pragma unroll
    for (int cc = 0; cc < 8; cc++) {
        int c = c0 + cc;
        float b = (c < 128) ? bq[c] : bk[c - 128];
#pragma unroll
        for (int rr = 0; rr < 8; rr++) acc[rr][cc] = b;
    }
    for (int kt = 0; kt < 4; kt++) {
#pragma unroll
        for (int v = 0; v < 8; v++) {
            int e = v * 1024 + tid * 4;
            int k = e >> 8, c = e & 255;
            float4 f;
            if (c < 128) f = *(const float4*)(Wq + (kt * 32 + k) * 128 + c);
            else f = *(const float4*)(Wk + (kt * 32 + k) * 128 + (c - 128));
            *(float4*)&ws[k][c] = f;
        }
        stage_x(xs, x, row0, kt, tid);
        __syncthreads();
#pragma unroll
        for (int kk = 0; kk < 32; kk++) {
            float4 w0 = *(const float4*)&ws[kk][c0];
            float4 w1 = *(const float4*)&ws[kk][c0 + 4];
            float4 xa = *(const float4*)&xs[kk][r0];
            float4 xb = *(const float4*)&xs[kk][r0 + 4];
            float xv[8] = {xa.x, xa.y, xa.z, xa.w, xb.x, xb.y, xb.z, xb.w};
            float wv[8] = {w0.x, w0.y, w0.z, w0.w, w1.x, w1.y, w1.z, w1.w};
#pragma unroll
            for (int rr = 0; rr < 8; rr++)
#pragma unroll
                for (int cc = 0; cc < 8; cc++) acc[rr][cc] += xv[rr] * wv[cc];
        }
        __syncthreads();
    }
#pragma unroll
    for (int rr = 0; rr < 8; rr++) {
        int gr = row0 + r0 + rr;
        if (gr >= NN) continue;
        float vals[8];
#pragma unroll
        for (int cc = 0; cc < 8; cc++) {
            float z = acc[rr][cc];
            vals[cc] = z > 0.f ? 1.f + z : __expf(z);
        }
        float* base;
        if (c0 < 128) {
            int hh = c0 >> 5, ii = c0 & 31;
            base = Qall + (size_t)hh * NN * 32 + (size_t)gr * 32 + ii;
        } else {
            int hh = (c0 - 128) >> 5, ii = (c0 - 128) & 31;
            base = Kall + (size_t)hh * NN * 32 + (size_t)gr * 32 + ii;
        }
        *(float4*)base = {vals[0], vals[1], vals[2], vals[3]};
        *(float4*)(base + 4) = {vals[4], vals[5], vals[6], vals[7]};
    }
}

__global__ __launch_bounds__(256) void v_kernel(const float* __restrict__ x,
                                                const float* __restrict__ Wv, const float* __restrict__ bv,
                                                float* __restrict__ Vall) {
    __shared__ float ws[32][40];
    __shared__ float xs[32][68];
    int tid = threadIdx.x;
    int row0 = blockIdx.x * 64;
    int cg = tid & 7, rg = tid >> 3;
    int c0 = cg * 5, r0 = rg * 2;
    float acc[2][5];
#pragma unroll
    for (int cc = 0; cc < 5; cc++) {
        float b = bv[c0 + cc];
        acc[0][cc] = b;
        acc[1][cc] = b;
    }
    for (int kt = 0; kt < 4; kt++) {
        for (int e = tid; e < 1280; e += 256) {
            int k = e / 40, c = e - 40 * k;
            ws[k][c] = Wv[(kt * 32 + k) * 40 + c];
        }
        stage_x(xs, x, row0, kt, tid);
        __syncthreads();
#pragma unroll
        for (int kk = 0; kk < 32; kk++) {
            float x0 = xs[kk][r0], x1 = xs[kk][r0 + 1];
#pragma unroll
            for (int cc = 0; cc < 5; cc++) {
                float w = ws[kk][c0 + cc];
                acc[0][cc] += x0 * w;
                acc[1][cc] += x1 * w;
            }
        }
        __syncthreads();
    }
#pragma unroll
    for (int rr = 0; rr < 2; rr++) {
        int gr = row0 + r0 + rr;
        if (gr >= NN) continue;
#pragma unroll
        for (int cc = 0; cc < 5; cc++) Vall[(size_t)gr * 40 + c0 + cc] = acc[rr][cc];
    }
}

__global__ void vinit_kernel(float* __restrict__ out, const float* __restrict__ Vall,
                             const float* __restrict__ hopwise) {
    int idx = blockIdx.x * blockDim.x + threadIdx.x;
    if (idx >= NN * NC) return;
    int n = idx / NC, c = idx - n * NC;
    const float* v = Vall + (size_t)n * 40 + c;
    out[idx] = hopwise[0] * (v[0] + v[10] + v[20] + v[30]);
}

// -------- bf16 pack/unpack helpers --------
__device__ __forceinline__ uint packbf(float a, float b) {
    __hip_bfloat162 t = __float22bfloat162_rn(float2{a, b});
    return *reinterpret_cast<uint*>(&t);
}
__device__ __forceinline__ float bflo(uint u) { return __uint_as_float(u << 16); }
__device__ __forceinline__ float bfhi(uint u) { return __uint_as_float(u & 0xFFFF0000u); }
__device__ __forceinline__ float bfs(ushort u) { return __uint_as_float(((uint)u) << 16); }

// -------- shared epilog: fold halves, H readout, out accumulate, write next --------
__device__ __forceinline__ void hop_epilog(float acc[10], float kacc, int gw, int lane, int i,
                                           const float* __restrict__ Qall_h,
                                           float* __restrict__ out,
                                           uint* __restrict__ Mnext, ushort* __restrict__ Knext,
                                           const float* __restrict__ hopwise,
                                           const float* __restrict__ headwise,
                                           int h, int hop, int write_next) {
#pragma unroll
    for (int c = 0; c < 10; c++) acc[c] += __shfl_xor(acc[c], 32);
    kacc += __shfl_xor(kacc, 32);

    float q = Qall_h[(size_t)gw * 32 + i];
    float num[10];
#pragma unroll
    for (int c = 0; c < 10; c++) num[c] = q * acc[c];
    float den = q * kacc;
#pragma unroll
    for (int off = 16; off >= 1; off >>= 1) {
#pragma unroll
        for (int c = 0; c < 10; c++) num[c] += __shfl_xor(num[c], off);
        den += __shfl_xor(den, off);
    }
    float e0 = __expf(headwise[0 * KHOPS + hop]);
    float e1 = __expf(headwise[1 * KHOPS + hop]);
    float e2 = __expf(headwise[2 * KHOPS + hop]);
    float e3 = __expf(headwise[3 * KHOPS + hop]);
    float eh = (h == 0) ? e0 : (h == 1) ? e1 : (h == 2) ? e2 : e3;
    float gamma = hopwise[hop + 1] * eh / (e0 + e1 + e2 + e3);
    float scale = gamma / (den + 1e-5f);
    if (lane < 10) {
        float v = lane == 0 ? num[0] : lane == 1 ? num[1] : lane == 2 ? num[2] :
                  lane == 3 ? num[3] : lane == 4 ? num[4] : lane == 5 ? num[5] :
                  lane == 6 ? num[6] : lane == 7 ? num[7] : lane == 8 ? num[8] : num[9];
        out[(size_t)gw * 10 + lane] += v * scale;
    }
    if (write_next && lane < 32) {
        uint* op = Mnext + (size_t)gw * 160 + i * 5;
        op[0] = packbf(acc[0], acc[1]);
        op[1] = packbf(acc[2], acc[3]);
        op[2] = packbf(acc[4], acc[5]);
        op[3] = packbf(acc[6], acc[7]);
        op[4] = packbf(acc[8], acc[9]);
        __hip_bfloat16 kb = __float2bfloat16(kacc);
        Knext[(size_t)gw * 32 + i] = *reinterpret_cast<ushort*>(&kb);
    }
}

// -------- hop 0 fused: gather K,V per edge, outer-product in registers --------
__global__ __launch_bounds__(256) void agg0_kernel(const float* __restrict__ Kall,
                                                   const float* __restrict__ Vall,
                                                   const float* __restrict__ Qall,
                                                   float* __restrict__ out,
                                                   uint* __restrict__ Mnext,
                                                   ushort* __restrict__ Knext,
                                                   const int* __restrict__ rowptr,
                                                   const int* __restrict__ srows,
                                                   const float* __restrict__ hopwise,
                                                   const float* __restrict__ headwise,
                                                   int h) {
    int gw = (blockIdx.x * 256 + threadIdx.x) >> 6;
    int lane = threadIdx.x & 63;
    int half = lane >> 5, i = lane & 31;
    int beg = rowptr[gw], end = rowptr[gw + 1];
    const float* Kh = Kall + (size_t)h * NN * 32;
    float acc[10] = {0.f, 0.f, 0.f, 0.f, 0.f, 0.f, 0.f, 0.f, 0.f, 0.f};
    float kacc = 0.f;
    int e = beg + half;
    for (; e + 2 < end; e += 4) {
        int s0 = srows[e], s1 = srows[e + 2];
        float k0 = Kh[(size_t)s0 * 32 + i];
        float k1 = Kh[(size_t)s1 * 32 + i];
        const float2* v0p = (const float2*)(Vall + (size_t)s0 * 40 + h * 10);
        const float2* v1p = (const float2*)(Vall + (size_t)s1 * 40 + h * 10);
        float2 a0 = v0p[0], a1 = v0p[1], a2 = v0p[2], a3 = v0p[3], a4 = v0p[4];
        float2 b0 = v1p[0], b1 = v1p[1], b2 = v1p[2], b3 = v1p[3], b4 = v1p[4];
        kacc += k0 + k1;
        acc[0] += k0 * a0.x + k1 * b0.x; acc[1] += k0 * a0.y + k1 * b0.y;
        acc[2] += k0 * a1.x + k1 * b1.x; acc[3] += k0 * a1.y + k1 * b1.y;
        acc[4] += k0 * a2.x + k1 * b2.x; acc[5] += k0 * a2.y + k1 * b2.y;
        acc[6] += k0 * a3.x + k1 * b3.x; acc[7] += k0 * a3.y + k1 * b3.y;
        acc[8] += k0 * a4.x + k1 * b4.x; acc[9] += k0 * a4.y + k1 * b4.y;
    }
    for (; e < end; e += 2) {
        int src = srows[e];
        float kv = Kh[(size_t)src * 32 + i];
        const float2* vp = (const float2*)(Vall + (size_t)src * 40 + h * 10);
        float2 a0 = vp[0], a1 = vp[1], a2 = vp[2], a3 = vp[3], a4 = vp[4];
        kacc += kv;
        acc[0] += kv * a0.x; acc[1] += kv * a0.y;
        acc[2] += kv * a1.x; acc[3] += kv * a1.y;
        acc[4] += kv * a2.x; acc[5] += kv * a2.y;
        acc[6] += kv * a3.x; acc[7] += kv * a3.y;
        acc[8] += kv * a4.x; acc[9] += kv * a4.y;
    }
    hop_epilog(acc, kacc, gw, lane, i, Qall + (size_t)h * NN * 32, out, Mnext, Knext,
               hopwise, headwise, h, 0, 1);
}

// -------- hops >=1: gather bf16 M,K; 2 edges/half in flight --------
__global__ __launch_bounds__(256) void agg_kernel(const uint* __restrict__ Mcur,
                                                  const ushort* __restrict__ Kcur,
                                                  const float* __restrict__ Qall,
                                                  float* __restrict__ out,
                                                  uint* __restrict__ Mnext,
                                                  ushort* __restrict__ Knext,
                                                  const int* __restrict__ rowptr,
                                                  const int* __restrict__ srows,
                                                  const float* __restrict__ hopwise,
                                                  const float* __restrict__ headwise,
                                                  int h, int hop, int write_next) {
    int gw = (blockIdx.x * 256 + threadIdx.x) >> 6;
    int lane = threadIdx.x & 63;
    int half = lane >> 5, i = lane & 31;
    int beg = rowptr[gw], end = rowptr[gw + 1];
    float acc[10] = {0.f, 0.f, 0.f, 0.f, 0.f, 0.f, 0.f, 0.f, 0.f, 0.f};
    float kacc = 0.f;
    int e = beg + half;
    for (; e + 2 < end; e += 4) {
        int s0 = srows[e], s1 = srows[e + 2];
        const uint* m0 = Mcur + (size_t)s0 * 160 + i * 5;
        const uint* m1 = Mcur + (size_t)s1 * 160 + i * 5;
        uint a0 = m0[0], a1 = m0[1], a2 = m0[2], a3 = m0[3], a4 = m0[4];
        uint b0 = m1[0], b1 = m1[1], b2 = m1[2], b3 = m1[3], b4 = m1[4];
        float k0 = bfs(Kcur[(size_t)s0 * 32 + i]);
        float k1 = bfs(Kcur[(size_t)s1 * 32 + i]);
        kacc += k0 + k1;
        acc[0] += bflo(a0) + bflo(b0); acc[1] += bfhi(a0) + bfhi(b0);
        acc[2] += bflo(a1) + bflo(b1); acc[3] += bfhi(a1) + bfhi(b1);
        acc[4] += bflo(a2) + bflo(b2); acc[5] += bfhi(a2) + bfhi(b2);
        acc[6] += bflo(a3) + bflo(b3); acc[7] += bfhi(a3) + bfhi(b3);
        acc[8] += bflo(a4) + bflo(b4); acc[9] += bfhi(a4) + bfhi(b4);
    }
    for (; e < end; e += 2) {
        int src = srows[e];
        const uint* mp = Mcur + (size_t)src * 160 + i * 5;
        uint a0 = mp[0], a1 = mp[1], a2 = mp[2], a3 = mp[3], a4 = mp[4];
        kacc += bfs(Kcur[(size_t)src * 32 + i]);
        acc[0] += bflo(a0); acc[1] += bfhi(a0);
        acc[2] += bflo(a1); acc[3] += bfhi(a1);
        acc[4] += bflo(a2); acc[5] += bfhi(a2);
        acc[6] += bflo(a3); acc[7] += bfhi(a3);
        acc[8] += bflo(a4); acc[9] += bfhi(a4);
    }
    hop_epilog(acc, kacc, gw, lane, i, Qall + (size_t)h * NN * 32, out, Mnext, Knext,
               hopwise, headwise, h, hop, write_next);
}

extern "C" void kernel_launch(void* const* d_in, const int* in_sizes, int n_in,
                              void* d_out, int out_size, void* d_ws, size_t ws_size,
                              hipStream_t stream) {
    const float* nf = (const float*)d_in[0];
    const int* ei = (const int*)d_in[1];
    const float* Wt = (const float*)d_in[2];
    const float* bt = (const float*)d_in[3];
    const float* Wq = (const float*)d_in[4];
    const float* bq = (const float*)d_in[5];
    const float* Wk = (const float*)d_in[6];
    const float* bk = (const float*)d_in[7];
    const float* Wv = (const float*)d_in[8];
    const float* bv = (const float*)d_in[9];
    const float* hopwise = (const float*)d_in[10];
    const float* headwise = (const float*)d_in[11];
    float* out = (float*)d_out;

    char* p = (char*)d_ws;
    auto alloc = [&](size_t bytes) {
        char* r = p;
        p += (bytes + 255) & ~(size_t)255;
        return r;
    };
    int* rowptr = (int*)alloc((NN + 4) * sizeof(int));
    int* cursor = (int*)alloc((NN + 4) * sizeof(int));
    int* bsum = (int*)alloc(NBLK * sizeof(int));
    int* boff = (int*)alloc(NBLK * sizeof(int));
    int* srows = (int*)alloc((size_t)NE * sizeof(int));
    int* flag = (int*)alloc(sizeof(int));
    float* x = (float*)alloc((size_t)NN * HID * sizeof(float));
    float* Qall = (float*)alloc((size_t)NH * NN * HC * sizeof(float));
    float* Kall = (float*)alloc((size_t)NH * NN * HC * sizeof(float));
    float* Vall = (float*)alloc((size_t)NN * 40 * sizeof(float));
    uint* Ma = (uint*)alloc((size_t)NN * 160 * sizeof(uint));
    uint* Mb = (uint*)alloc((size_t)NN * 160 * sizeof(uint));
    ushort* Ka = (ushort*)alloc((size_t)NN * 32 * sizeof(ushort));
    ushort* Kb = (ushort*)alloc((size_t)NN * 32 * sizeof(ushort));

    detect_kernel<<<1, 64, 0, stream>>>(ei, flag);
    zero_kernel<<<(NN + 255) / 256, 256, 0, stream>>>(cursor, NN);
    hist_kernel<<<(NE + 255) / 256, 256, 0, stream>>>(ei, flag, cursor);
    bsum_kernel<<<NBLK, 256, 0, stream>>>(cursor, bsum);
    bscan_kernel<<<1, 64, 0, stream>>>(bsum, boff, rowptr);
    scanb_kernel<<<NBLK, 256, 0, stream>>>(cursor, boff, rowptr, cursor);
    scatter_kernel<<<(NE + 255) / 256, 256, 0, stream>>>(ei, flag, cursor, srows);

    int nrb = (NN + 63) / 64;
    x_kernel<<<nrb, 256, 0, stream>>>(nf, Wt, bt, x);
    qk_kernel<<<nrb, 256, 0, stream>>>(x, Wq, bq, Wk, bk, Qall, Kall);
    v_kernel<<<nrb, 256, 0, stream>>>(x, Wv, bv, Vall);
    vinit_kernel<<<(NN * NC + 255) / 256, 256, 0, stream>>>(out, Vall, hopwise);

    for (int h = 0; h < NH; h++) {
        // hop 0: fused outer-product gather, writes M1 -> Ma, K1 -> Ka
        agg0_kernel<<<NN / 4, 256, 0, stream>>>(Kall, Vall, Qall, out, Ma, Ka,
                                                rowptr, srows, hopwise, headwise, h);
        // hop 1: Ma -> Mb
        agg_kernel<<<NN / 4, 256, 0, stream>>>(Ma, Ka, Qall, out, Mb, Kb,
                                               rowptr, srows, hopwise, headwise, h, 1, 1);
        // hop 2: Mb -> (no write)
        agg_kernel<<<NN / 4, 256, 0, stream>>>(Mb, Kb, Qall, out, Ma, Ka,
                                               rowptr, srows, hopwise, headwise, h, 2, 0);
    }
}

// Round 4
// 699.384 us; speedup vs baseline: 2.7981x; 1.0902x over previous
//
#include <hip/hip_runtime.h>
#include <hip/hip_bf16.h>

#define NN 50000
#define NE 400000
#define NF 128
#define HID 128
#define NH 4
#define HC 32
#define NC 10
#define KHOPS 3
#define NBLK ((NN + 1023) / 1024)   // 49

typedef unsigned int uint;
typedef unsigned short ushort;
typedef __attribute__((ext_vector_type(8))) short bf16x8;
typedef __attribute__((ext_vector_type(4))) float f32x4;

// -------- edge dtype detect: int64 (odd words all zero) vs int32 --------
__global__ void detect_kernel(const int* __restrict__ ei, int* __restrict__ flag) {
    int w = ei[2 * threadIdx.x + 1];
    unsigned long long b = __ballot(w != 0);
    if (threadIdx.x == 0) *flag = (b == 0ULL) ? 1 : 0;  // 1 => int64
}

__device__ __forceinline__ int edge_row(const int* ei, int is64, int e) {
    return is64 ? ei[2 * e] : ei[e];
}
__device__ __forceinline__ int edge_col(const int* ei, int is64, int e) {
    return is64 ? ei[2 * NE + 2 * e] : ei[NE + e];
}

__global__ void zero_kernel(int* __restrict__ p, int n) {
    int i = blockIdx.x * blockDim.x + threadIdx.x;
    if (i < n) p[i] = 0;
}

__global__ void hist_kernel(const int* __restrict__ ei, const int* __restrict__ flag,
                            int* __restrict__ counts) {
    int e = blockIdx.x * blockDim.x + threadIdx.x;
    if (e >= NE) return;
    int c = edge_col(ei, *flag, e);
    atomicAdd(&counts[c], 1);
}

// ---- hierarchical scan ----
__global__ __launch_bounds__(256) void bsum_kernel(const int* __restrict__ counts,
                                                   int* __restrict__ bsum) {
    int b = blockIdx.x, tid = threadIdx.x;
    int base = b * 1024 + tid * 4;
    int4 v = {0, 0, 0, 0};
    if (base < NN) v = *(const int4*)(counts + base);
    int s = v.x + v.y + v.z + v.w;
#pragma unroll
    for (int off = 32; off >= 1; off >>= 1) s += __shfl_xor(s, off);
    __shared__ int ws[4];
    int lane = tid & 63, w = tid >> 6;
    if (lane == 0) ws[w] = s;
    __syncthreads();
    if (tid == 0) bsum[b] = ws[0] + ws[1] + ws[2] + ws[3];
}

__global__ void bscan_kernel(const int* __restrict__ bsum, int* __restrict__ boff,
                             int* __restrict__ rowptr) {
    int lane = threadIdx.x;
    int v = (lane < NBLK) ? bsum[lane] : 0;
    int t = v;
#pragma unroll
    for (int off = 1; off < 64; off <<= 1) {
        int u = __shfl_up(t, off);
        if (lane >= off) t += u;
    }
    if (lane < NBLK) boff[lane] = t - v;
    if (lane == NBLK - 1) rowptr[NN] = t;
}

__global__ __launch_bounds__(256) void scanb_kernel(const int* __restrict__ counts,
                                                    const int* __restrict__ boff,
                                                    int* __restrict__ rowptr,
                                                    int* __restrict__ cursor) {
    int b = blockIdx.x, tid = threadIdx.x;
    int base = b * 1024 + tid * 4;
    int4 v = {0, 0, 0, 0};
    if (base < NN) v = *(const int4*)(counts + base);
    int s3 = v.x + v.y + v.z + v.w;
    int lane = tid & 63, w = tid >> 6;
    int t = s3;
#pragma unroll
    for (int off = 1; off < 64; off <<= 1) {
        int u = __shfl_up(t, off);
        if (lane >= off) t += u;
    }
    __shared__ int ws[4];
    if (lane == 63) ws[w] = t;
    __syncthreads();
    int wofs = boff[b];
    for (int i = 0; i < 4; i++) wofs += (i < w) ? ws[i] : 0;
    int excl = wofs + t - s3;
    if (base < NN) {
        int4 o;
        o.x = excl;
        o.y = excl + v.x;
        o.z = o.y + v.y;
        o.w = o.z + v.z;
        *(int4*)(rowptr + base) = o;
        *(int4*)(cursor + base) = o;
    }
}

__global__ void scatter_kernel(const int* __restrict__ ei, const int* __restrict__ flag,
                               int* __restrict__ cursor, int* __restrict__ srows) {
    int e = blockIdx.x * blockDim.x + threadIdx.x;
    if (e >= NE) return;
    int is64 = *flag;
    int r = edge_row(ei, is64, e);
    int c = edge_col(ei, is64, e);
    int pos = atomicAdd(&cursor[c], 1);
    srows[pos] = r;
}

// -------- bf16 helpers --------
__device__ __forceinline__ short bfbits(float f) {
    __hip_bfloat16 h = __float2bfloat16(f);
    return *reinterpret_cast<short*>(&h);
}
__device__ __forceinline__ ushort bfbitsu(float f) {
    __hip_bfloat16 h = __float2bfloat16(f);
    return *reinterpret_cast<ushort*>(&h);
}
__device__ __forceinline__ uint packbf(float a, float b) {
    __hip_bfloat162 t = __float22bfloat162_rn(float2{a, b});
    return *reinterpret_cast<uint*>(&t);
}
__device__ __forceinline__ float bflo(uint u) { return __uint_as_float(u << 16); }
__device__ __forceinline__ float bfhi(uint u) { return __uint_as_float(u & 0xFFFF0000u); }
__device__ __forceinline__ float bfs(ushort u) { return __uint_as_float(((uint)u) << 16); }

// -------- weight convert: bf16, transposed [col][k] --------
__global__ void wconv_kernel(const float* __restrict__ Wt, const float* __restrict__ Wq,
                             const float* __restrict__ Wk, const float* __restrict__ Wv,
                             ushort* __restrict__ Wtb, ushort* __restrict__ Wqkvb) {
    int idx = blockIdx.x * 256 + threadIdx.x;
    if (idx < 128 * 128) {
        int c = idx >> 7, k = idx & 127;
        Wtb[c * 128 + k] = bfbitsu(Wt[k * 128 + c]);
    }
    if (idx < 304 * 128) {
        int c = idx >> 7, k = idx & 127;
        float w;
        if (c < 128) w = Wq[k * 128 + c];
        else if (c < 256) w = Wk[k * 128 + (c - 128)];
        else { int cv = c - 256; w = (cv < 40) ? Wv[k * 40 + cv] : 0.f; }
        Wqkvb[c * 128 + k] = bfbitsu(w);
    }
}

// -------- x = relu(nf @ Wt + bt), MFMA, register-direct, output bf16 --------
__global__ __launch_bounds__(256) void xm_kernel(const float* __restrict__ nf,
                                                 const ushort* __restrict__ Wtb,
                                                 const float* __restrict__ bt,
                                                 ushort* __restrict__ xb) {
    int wid = threadIdx.x >> 6, lane = threadIdx.x & 63;
    int row0 = blockIdx.x * 64 + wid * 16;
    int r = lane & 15, kg = lane >> 4;
    int ar = row0 + r;
    if (ar > NN - 1) ar = NN - 1;
    f32x4 acc[8];
#pragma unroll
    for (int ct = 0; ct < 8; ct++) acc[ct] = f32x4{0.f, 0.f, 0.f, 0.f};
#pragma unroll
    for (int ks = 0; ks < 4; ks++) {
        int k0 = ks * 32 + kg * 8;
        const float4* ap = (const float4*)(nf + (size_t)ar * 128 + k0);
        float4 a0 = ap[0], a1 = ap[1];
        bf16x8 af;
        af[0] = bfbits(a0.x); af[1] = bfbits(a0.y); af[2] = bfbits(a0.z); af[3] = bfbits(a0.w);
        af[4] = bfbits(a1.x); af[5] = bfbits(a1.y); af[6] = bfbits(a1.z); af[7] = bfbits(a1.w);
#pragma unroll
        for (int ct = 0; ct < 8; ct++) {
            bf16x8 bf = *(const bf16x8*)(Wtb + (size_t)(ct * 16 + r) * 128 + k0);
            acc[ct] = __builtin_amdgcn_mfma_f32_16x16x32_bf16(af, bf, acc[ct], 0, 0, 0);
        }
    }
#pragma unroll
    for (int ct = 0; ct < 8; ct++) {
        int c = ct * 16 + r;
        float b = bt[c];
#pragma unroll
        for (int reg = 0; reg < 4; reg++) {
            int n = row0 + kg * 4 + reg;
            if (n < NN) {
                float z = acc[ct][reg] + b;
                xb[(size_t)n * 128 + c] = bfbitsu(fmaxf(z, 0.f));
            }
        }
    }
}

// -------- fused QKV: Q f32 [h][n][32], K bf16 [h][n][32], V bf16 [n][4*16 padded] --------
__global__ __launch_bounds__(256) void qkv_kernel(const ushort* __restrict__ xb,
                                                  const ushort* __restrict__ Wqkvb,
                                                  const float* __restrict__ bq,
                                                  const float* __restrict__ bk,
                                                  const float* __restrict__ bv,
                                                  float* __restrict__ Qall,
                                                  ushort* __restrict__ Kbf,
                                                  ushort* __restrict__ Vbf) {
    int wid = threadIdx.x >> 6, lane = threadIdx.x & 63;
    int row0 = blockIdx.x * 64 + wid * 16;
    int r = lane & 15, kg = lane >> 4;
    int ar = row0 + r;
    if (ar > NN - 1) ar = NN - 1;
    f32x4 acc[19];
#pragma unroll
    for (int ct = 0; ct < 19; ct++) acc[ct] = f32x4{0.f, 0.f, 0.f, 0.f};
#pragma unroll
    for (int ks = 0; ks < 4; ks++) {
        int k0 = ks * 32 + kg * 8;
        bf16x8 af = *(const bf16x8*)(xb + (size_t)ar * 128 + k0);
#pragma unroll
        for (int ct = 0; ct < 19; ct++) {
            bf16x8 bf = *(const bf16x8*)(Wqkvb + (size_t)(ct * 16 + r) * 128 + k0);
            acc[ct] = __builtin_amdgcn_mfma_f32_16x16x32_bf16(af, bf, acc[ct], 0, 0, 0);
        }
    }
#pragma unroll
    for (int ct = 0; ct < 19; ct++) {
        int c = ct * 16 + r;
        float bias;
        if (c < 128) bias = bq[c];
        else if (c < 256) bias = bk[c - 128];
        else { int cv = c - 256; bias = (cv < 40) ? bv[cv] : 0.f; }
#pragma unroll
        for (int reg = 0; reg < 4; reg++) {
            int n = row0 + kg * 4 + reg;
            if (n >= NN) continue;
            float z = acc[ct][reg] + bias;
            if (c < 128) {
                float q = z > 0.f ? 1.f + z : __expf(z);
                Qall[(size_t)(c >> 5) * NN * 32 + (size_t)n * 32 + (c & 31)] = q;
            } else if (c < 256) {
                int cc = c - 128;
                float kv = z > 0.f ? 1.f + z : __expf(z);
                Kbf[(size_t)(cc >> 5) * NN * 32 + (size_t)n * 32 + (cc & 31)] = bfbitsu(kv);
            } else {
                int cv = c - 256;
                if (cv < 40) {
                    int hh = cv / 10, cc = cv - hh * 10;
                    Vbf[(size_t)n * 64 + hh * 16 + cc] = bfbitsu(z);
                }
            }
        }
    }
}

// -------- out init: out[n,c] = hopwise[0] * sum_h V[n,h,c] --------
__global__ void vinit_kernel(float* __restrict__ out, const ushort* __restrict__ Vbf,
                             const float* __restrict__ hopwise) {
    int idx = blockIdx.x * blockDim.x + threadIdx.x;
    if (idx >= NN * NC) return;
    int n = idx / NC, c = idx - n * NC;
    const ushort* v = Vbf + (size_t)n * 64 + c;
    out[idx] = hopwise[0] * (bfs(v[0]) + bfs(v[16]) + bfs(v[32]) + bfs(v[48]));
}

// -------- shared epilog --------
__device__ __forceinline__ void hop_epilog(float acc[10], float kacc, int gw, int lane, int i,
                                           const float* __restrict__ Qall_h,
                                           float* __restrict__ out,
                                           uint* __restrict__ Mnext, ushort* __restrict__ Knext,
                                           const float* __restrict__ hopwise,
                                           const float* __restrict__ headwise,
                                           int h, int hop, int write_next) {
#pragma unroll
    for (int c = 0; c < 10; c++) acc[c] += __shfl_xor(acc[c], 32);
    kacc += __shfl_xor(kacc, 32);

    float q = Qall_h[(size_t)gw * 32 + i];
    float num[10];
#pragma unroll
    for (int c = 0; c < 10; c++) num[c] = q * acc[c];
    float den = q * kacc;
#pragma unroll
    for (int off = 16; off >= 1; off >>= 1) {
#pragma unroll
        for (int c = 0; c < 10; c++) num[c] += __shfl_xor(num[c], off);
        den += __shfl_xor(den, off);
    }
    float e0 = __expf(headwise[0 * KHOPS + hop]);
    float e1 = __expf(headwise[1 * KHOPS + hop]);
    float e2 = __expf(headwise[2 * KHOPS + hop]);
    float e3 = __expf(headwise[3 * KHOPS + hop]);
    float eh = (h == 0) ? e0 : (h == 1) ? e1 : (h == 2) ? e2 : e3;
    float gamma = hopwise[hop + 1] * eh / (e0 + e1 + e2 + e3);
    float scale = gamma / (den + 1e-5f);
    if (lane < 10) {
        float v = lane == 0 ? num[0] : lane == 1 ? num[1] : lane == 2 ? num[2] :
                  lane == 3 ? num[3] : lane == 4 ? num[4] : lane == 5 ? num[5] :
                  lane == 6 ? num[6] : lane == 7 ? num[7] : lane == 8 ? num[8] : num[9];
        out[(size_t)gw * 10 + lane] += v * scale;
    }
    if (write_next && lane < 32) {
        uint* op = Mnext + (size_t)gw * 160 + i * 5;
        op[0] = packbf(acc[0], acc[1]);
        op[1] = packbf(acc[2], acc[3]);
        op[2] = packbf(acc[4], acc[5]);
        op[3] = packbf(acc[6], acc[7]);
        op[4] = packbf(acc[8], acc[9]);
        Knext[(size_t)gw * 32 + i] = bfbitsu(kacc);
    }
}

// -------- hop 0: gather bf16 K,V; outer-product in registers --------
__global__ __launch_bounds__(256) void agg0_kernel(const ushort* __restrict__ Kbf,
                                                   const ushort* __restrict__ Vbf,
                                                   const float* __restrict__ Qall,
                                                   float* __restrict__ out,
                                                   uint* __restrict__ Mnext,
                                                   ushort* __restrict__ Knext,
                                                   const int* __restrict__ rowptr,
                                                   const int* __restrict__ srows,
                                                   const float* __restrict__ hopwise,
                                                   const float* __restrict__ headwise,
                                                   int h) {
    int gw = (blockIdx.x * 256 + threadIdx.x) >> 6;
    int lane = threadIdx.x & 63;
    int half = lane >> 5, i = lane & 31;
    int beg = rowptr[gw], end = rowptr[gw + 1];
    const ushort* Kh = Kbf + (size_t)h * NN * 32;
    float acc[10] = {0.f, 0.f, 0.f, 0.f, 0.f, 0.f, 0.f, 0.f, 0.f, 0.f};
    float kacc = 0.f;
    int e = beg + half;
    for (; e + 2 < end; e += 4) {
        int s0 = srows[e], s1 = srows[e + 2];
        float k0 = bfs(Kh[(size_t)s0 * 32 + i]);
        float k1 = bfs(Kh[(size_t)s1 * 32 + i]);
        const ushort* v0b = Vbf + (size_t)s0 * 64 + h * 16;
        const ushort* v1b = Vbf + (size_t)s1 * 64 + h * 16;
        uint4 a4 = *(const uint4*)v0b;
        uint a5 = *(const uint*)(v0b + 8);
        uint4 b4 = *(const uint4*)v1b;
        uint b5 = *(const uint*)(v1b + 8);
        kacc += k0 + k1;
        acc[0] += k0 * bflo(a4.x) + k1 * bflo(b4.x); acc[1] += k0 * bfhi(a4.x) + k1 * bfhi(b4.x);
        acc[2] += k0 * bflo(a4.y) + k1 * bflo(b4.y); acc[3] += k0 * bfhi(a4.y) + k1 * bfhi(b4.y);
        acc[4] += k0 * bflo(a4.z) + k1 * bflo(b4.z); acc[5] += k0 * bfhi(a4.z) + k1 * bfhi(b4.z);
        acc[6] += k0 * bflo(a4.w) + k1 * bflo(b4.w); acc[7] += k0 * bfhi(a4.w) + k1 * bfhi(b4.w);
        acc[8] += k0 * bflo(a5) + k1 * bflo(b5);     acc[9] += k0 * bfhi(a5) + k1 * bfhi(b5);
    }
    for (; e < end; e += 2) {
        int src = srows[e];
        float kv = bfs(Kh[(size_t)src * 32 + i]);
        const ushort* vb = Vbf + (size_t)src * 64 + h * 16;
        uint4 a4 = *(const uint4*)vb;
        uint a5 = *(const uint*)(vb + 8);
        kacc += kv;
        acc[0] += kv * bflo(a4.x); acc[1] += kv * bfhi(a4.x);
        acc[2] += kv * bflo(a4.y); acc[3] += kv * bfhi(a4.y);
        acc[4] += kv * bflo(a4.z); acc[5] += kv * bfhi(a4.z);
        acc[6] += kv * bflo(a4.w); acc[7] += kv * bfhi(a4.w);
        acc[8] += kv * bflo(a5);   acc[9] += kv * bfhi(a5);
    }
    hop_epilog(acc, kacc, gw, lane, i, Qall + (size_t)h * NN * 32, out, Mnext, Knext,
               hopwise, headwise, h, 0, 1);
}

// -------- hops >=1: gather bf16 M,K --------
__global__ __launch_bounds__(256) void agg_kernel(const uint* __restrict__ Mcur,
                                                  const ushort* __restrict__ Kcur,
                                                  const float* __restrict__ Qall,
                                                  float* __restrict__ out,
                                                  uint* __restrict__ Mnext,
                                                  ushort* __restrict__ Knext,
                                                  const int* __restrict__ rowptr,
                                                  const int* __restrict__ srows,
                                                  const float* __restrict__ hopwise,
                                                  const float* __restrict__ headwise,
                                                  int h, int hop, int write_next) {
    int gw = (blockIdx.x * 256 + threadIdx.x) >> 6;
    int lane = threadIdx.x & 63;
    int half = lane >> 5, i = lane & 31;
    int beg = rowptr[gw], end = rowptr[gw + 1];
    float acc[10] = {0.f, 0.f, 0.f, 0.f, 0.f, 0.f, 0.f, 0.f, 0.f, 0.f};
    float kacc = 0.f;
    int e = beg + half;
    for (; e + 2 < end; e += 4) {
        int s0 = srows[e], s1 = srows[e + 2];
        const uint* m0 = Mcur + (size_t)s0 * 160 + i * 5;
        const uint* m1 = Mcur + (size_t)s1 * 160 + i * 5;
        uint a0 = m0[0], a1 = m0[1], a2 = m0[2], a3 = m0[3], a4 = m0[4];
        uint b0 = m1[0], b1 = m1[1], b2 = m1[2], b3 = m1[3], b4 = m1[4];
        float k0 = bfs(Kcur[(size_t)s0 * 32 + i]);
        float k1 = bfs(Kcur[(size_t)s1 * 32 + i]);
        kacc += k0 + k1;
        acc[0] += bflo(a0) + bflo(b0); acc[1] += bfhi(a0) + bfhi(b0);
        acc[2] += bflo(a1) + bflo(b1); acc[3] += bfhi(a1) + bfhi(b1);
        acc[4] += bflo(a2) + bflo(b2); acc[5] += bfhi(a2) + bfhi(b2);
        acc[6] += bflo(a3) + bflo(b3); acc[7] += bfhi(a3) + bfhi(b3);
        acc[8] += bflo(a4) + bflo(b4); acc[9] += bfhi(a4) + bfhi(b4);
    }
    for (; e < end; e += 2) {
        int src = srows[e];
        const uint* mp = Mcur + (size_t)src * 160 + i * 5;
        uint a0 = mp[0], a1 = mp[1], a2 = mp[2], a3 = mp[3], a4 = mp[4];
        kacc += bfs(Kcur[(size_t)src * 32 + i]);
        acc[0] += bflo(a0); acc[1] += bfhi(a0);
        acc[2] += bflo(a1); acc[3] += bfhi(a1);
        acc[4] += bflo(a2); acc[5] += bfhi(a2);
        acc[6] += bflo(a3); acc[7] += bfhi(a3);
        acc[8] += bflo(a4); acc[9] += bfhi(a4);
    }
    hop_epilog(acc, kacc, gw, lane, i, Qall + (size_t)h * NN * 32, out, Mnext, Knext,
               hopwise, headwise, h, hop, write_next);
}

extern "C" void kernel_launch(void* const* d_in, const int* in_sizes, int n_in,
                              void* d_out, int out_size, void* d_ws, size_t ws_size,
                              hipStream_t stream) {
    const float* nf = (const float*)d_in[0];
    const int* ei = (const int*)d_in[1];
    const float* Wt = (const float*)d_in[2];
    const float* bt = (const float*)d_in[3];
    const float* Wq = (const float*)d_in[4];
    const float* bq = (const float*)d_in[5];
    const float* Wk = (const float*)d_in[6];
    const float* bk = (const float*)d_in[7];
    const float* Wv = (const float*)d_in[8];
    const float* bv = (const float*)d_in[9];
    const float* hopwise = (const float*)d_in[10];
    const float* headwise = (const float*)d_in[11];
    float* out = (float*)d_out;

    char* p = (char*)d_ws;
    auto alloc = [&](size_t bytes) {
        char* r = p;
        p += (bytes + 255) & ~(size_t)255;
        return r;
    };
    int* rowptr = (int*)alloc((NN + 4) * sizeof(int));
    int* cursor = (int*)alloc((NN + 4) * sizeof(int));
    int* bsum = (int*)alloc(NBLK * sizeof(int));
    int* boff = (int*)alloc(NBLK * sizeof(int));
    int* srows = (int*)alloc((size_t)NE * sizeof(int));
    int* flag = (int*)alloc(sizeof(int));
    ushort* Wtb = (ushort*)alloc(128 * 128 * sizeof(ushort));
    ushort* Wqkvb = (ushort*)alloc(304 * 128 * sizeof(ushort));
    ushort* xb = (ushort*)alloc((size_t)NN * 128 * sizeof(ushort));
    float* Qall = (float*)alloc((size_t)NH * NN * HC * sizeof(float));
    ushort* Kbf = (ushort*)alloc((size_t)NH * NN * HC * sizeof(ushort));
    ushort* Vbf = (ushort*)alloc((size_t)NN * 64 * sizeof(ushort));
    uint* Ma = (uint*)alloc((size_t)NN * 160 * sizeof(uint));
    uint* Mb = (uint*)alloc((size_t)NN * 160 * sizeof(uint));
    ushort* Ka = (ushort*)alloc((size_t)NN * 32 * sizeof(ushort));
    ushort* Kb = (ushort*)alloc((size_t)NN * 32 * sizeof(ushort));

    detect_kernel<<<1, 64, 0, stream>>>(ei, flag);
    zero_kernel<<<(NN + 255) / 256, 256, 0, stream>>>(cursor, NN);
    hist_kernel<<<(NE + 255) / 256, 256, 0, stream>>>(ei, flag, cursor);
    bsum_kernel<<<NBLK, 256, 0, stream>>>(cursor, bsum);
    bscan_kernel<<<1, 64, 0, stream>>>(bsum, boff, rowptr);
    scanb_kernel<<<NBLK, 256, 0, stream>>>(cursor, boff, rowptr, cursor);
    scatter_kernel<<<(NE + 255) / 256, 256, 0, stream>>>(ei, flag, cursor, srows);

    wconv_kernel<<<(304 * 128 + 255) / 256, 256, 0, stream>>>(Wt, Wq, Wk, Wv, Wtb, Wqkvb);
    int nrb = (NN + 63) / 64;
    xm_kernel<<<nrb, 256, 0, stream>>>(nf, Wtb, bt, xb);
    qkv_kernel<<<nrb, 256, 0, stream>>>(xb, Wqkvb, bq, bk, bv, Qall, Kbf, Vbf);
    vinit_kernel<<<(NN * NC + 255) / 256, 256, 0, stream>>>(out, Vbf, hopwise);

    for (int h = 0; h < NH; h++) {
        agg0_kernel<<<NN / 4, 256, 0, stream>>>(Kbf, Vbf, Qall, out, Ma, Ka,
                                                rowptr, srows, hopwise, headwise, h);
        agg_kernel<<<NN / 4, 256, 0, stream>>>(Ma, Ka, Qall, out, Mb, Kb,
                                               rowptr, srows, hopwise, headwise, h, 1, 1);
        agg_kernel<<<NN / 4, 256, 0, stream>>>(Mb, Kb, Qall, out, Ma, Ka,
                                               rowptr, srows, hopwise, headwise, h, 2, 0);
    }
}

// Round 5
// 676.057 us; speedup vs baseline: 2.8946x; 1.0345x over previous
//
#include <hip/hip_runtime.h>
#include <hip/hip_bf16.h>

#define NN 50000
#define NE 400000
#define NF 128
#define HID 128
#define NH 4
#define HC 32
#define NC 10
#define KHOPS 3
#define NBLK ((NN + 1023) / 1024)   // 49

typedef unsigned int uint;
typedef unsigned short ushort;
typedef __attribute__((ext_vector_type(8))) short bf16x8;
typedef __attribute__((ext_vector_type(4))) float f32x4;

// -------- edge dtype detect: int64 (odd words all zero) vs int32 --------
__global__ void detect_kernel(const int* __restrict__ ei, int* __restrict__ flag) {
    int w = ei[2 * threadIdx.x + 1];
    unsigned long long b = __ballot(w != 0);
    if (threadIdx.x == 0) *flag = (b == 0ULL) ? 1 : 0;  // 1 => int64
}

__device__ __forceinline__ int edge_row(const int* ei, int is64, int e) {
    return is64 ? ei[2 * e] : ei[e];
}
__device__ __forceinline__ int edge_col(const int* ei, int is64, int e) {
    return is64 ? ei[2 * NE + 2 * e] : ei[NE + e];
}

__global__ void zero_kernel(int* __restrict__ p, int n) {
    int i = blockIdx.x * blockDim.x + threadIdx.x;
    if (i < n) p[i] = 0;
}

__global__ void hist_kernel(const int* __restrict__ ei, const int* __restrict__ flag,
                            int* __restrict__ counts) {
    int e = blockIdx.x * blockDim.x + threadIdx.x;
    if (e >= NE) return;
    int c = edge_col(ei, *flag, e);
    atomicAdd(&counts[c], 1);
}

// ---- hierarchical scan ----
__global__ __launch_bounds__(256) void bsum_kernel(const int* __restrict__ counts,
                                                   int* __restrict__ bsum) {
    int b = blockIdx.x, tid = threadIdx.x;
    int base = b * 1024 + tid * 4;
    int4 v = {0, 0, 0, 0};
    if (base < NN) v = *(const int4*)(counts + base);
    int s = v.x + v.y + v.z + v.w;
#pragma unroll
    for (int off = 32; off >= 1; off >>= 1) s += __shfl_xor(s, off);
    __shared__ int ws[4];
    int lane = tid & 63, w = tid >> 6;
    if (lane == 0) ws[w] = s;
    __syncthreads();
    if (tid == 0) bsum[b] = ws[0] + ws[1] + ws[2] + ws[3];
}

__global__ void bscan_kernel(const int* __restrict__ bsum, int* __restrict__ boff,
                             int* __restrict__ rowptr) {
    int lane = threadIdx.x;
    int v = (lane < NBLK) ? bsum[lane] : 0;
    int t = v;
#pragma unroll
    for (int off = 1; off < 64; off <<= 1) {
        int u = __shfl_up(t, off);
        if (lane >= off) t += u;
    }
    if (lane < NBLK) boff[lane] = t - v;
    if (lane == NBLK - 1) rowptr[NN] = t;
}

__global__ __launch_bounds__(256) void scanb_kernel(const int* __restrict__ counts,
                                                    const int* __restrict__ boff,
                                                    int* __restrict__ rowptr,
                                                    int* __restrict__ cursor) {
    int b = blockIdx.x, tid = threadIdx.x;
    int base = b * 1024 + tid * 4;
    int4 v = {0, 0, 0, 0};
    if (base < NN) v = *(const int4*)(counts + base);
    int s3 = v.x + v.y + v.z + v.w;
    int lane = tid & 63, w = tid >> 6;
    int t = s3;
#pragma unroll
    for (int off = 1; off < 64; off <<= 1) {
        int u = __shfl_up(t, off);
        if (lane >= off) t += u;
    }
    __shared__ int ws[4];
    if (lane == 63) ws[w] = t;
    __syncthreads();
    int wofs = boff[b];
    for (int i = 0; i < 4; i++) wofs += (i < w) ? ws[i] : 0;
    int excl = wofs + t - s3;
    if (base < NN) {
        int4 o;
        o.x = excl;
        o.y = excl + v.x;
        o.z = o.y + v.y;
        o.w = o.z + v.z;
        *(int4*)(rowptr + base) = o;
        *(int4*)(cursor + base) = o;
    }
}

__global__ void scatter_kernel(const int* __restrict__ ei, const int* __restrict__ flag,
                               int* __restrict__ cursor, int* __restrict__ srows) {
    int e = blockIdx.x * blockDim.x + threadIdx.x;
    if (e >= NE) return;
    int is64 = *flag;
    int r = edge_row(ei, is64, e);
    int c = edge_col(ei, is64, e);
    int pos = atomicAdd(&cursor[c], 1);
    srows[pos] = r;
}

// -------- bf16 helpers --------
__device__ __forceinline__ short bfbits(float f) {
    __hip_bfloat16 h = __float2bfloat16(f);
    return *reinterpret_cast<short*>(&h);
}
__device__ __forceinline__ ushort bfbitsu(float f) {
    __hip_bfloat16 h = __float2bfloat16(f);
    return *reinterpret_cast<ushort*>(&h);
}
__device__ __forceinline__ uint packbf(float a, float b) {
    __hip_bfloat162 t = __float22bfloat162_rn(float2{a, b});
    return *reinterpret_cast<uint*>(&t);
}
__device__ __forceinline__ float bflo(uint u) { return __uint_as_float(u << 16); }
__device__ __forceinline__ float bfhi(uint u) { return __uint_as_float(u & 0xFFFF0000u); }
__device__ __forceinline__ float bfs(ushort u) { return __uint_as_float(((uint)u) << 16); }

// -------- weight convert: bf16, transposed [col][k] --------
__global__ void wconv_kernel(const float* __restrict__ Wt, const float* __restrict__ Wq,
                             const float* __restrict__ Wk, const float* __restrict__ Wv,
                             ushort* __restrict__ Wtb, ushort* __restrict__ Wqkvb) {
    int idx = blockIdx.x * 256 + threadIdx.x;
    if (idx < 128 * 128) {
        int c = idx >> 7, k = idx & 127;
        Wtb[c * 128 + k] = bfbitsu(Wt[k * 128 + c]);
    }
    if (idx < 304 * 128) {
        int c = idx >> 7, k = idx & 127;
        float w;
        if (c < 128) w = Wq[k * 128 + c];
        else if (c < 256) w = Wk[k * 128 + (c - 128)];
        else { int cv = c - 256; w = (cv < 40) ? Wv[k * 40 + cv] : 0.f; }
        Wqkvb[c * 128 + k] = bfbitsu(w);
    }
}

// -------- x = relu(nf @ Wt + bt), MFMA, column-split over gridDim.y --------
__global__ __launch_bounds__(256) void xm_kernel(const float* __restrict__ nf,
                                                 const ushort* __restrict__ Wtb,
                                                 const float* __restrict__ bt,
                                                 ushort* __restrict__ xb) {
    int wid = threadIdx.x >> 6, lane = threadIdx.x & 63;
    int row0 = blockIdx.x * 64 + wid * 16;
    int r = lane & 15, kg = lane >> 4;
    int ar = row0 + r;
    if (ar > NN - 1) ar = NN - 1;
    int ctbeg = blockIdx.y * 4;
    f32x4 acc[4];
#pragma unroll
    for (int ct = 0; ct < 4; ct++) acc[ct] = f32x4{0.f, 0.f, 0.f, 0.f};
#pragma unroll
    for (int ks = 0; ks < 4; ks++) {
        int k0 = ks * 32 + kg * 8;
        const float4* ap = (const float4*)(nf + (size_t)ar * 128 + k0);
        float4 a0 = ap[0], a1 = ap[1];
        bf16x8 af;
        af[0] = bfbits(a0.x); af[1] = bfbits(a0.y); af[2] = bfbits(a0.z); af[3] = bfbits(a0.w);
        af[4] = bfbits(a1.x); af[5] = bfbits(a1.y); af[6] = bfbits(a1.z); af[7] = bfbits(a1.w);
#pragma unroll
        for (int ct = 0; ct < 4; ct++) {
            bf16x8 bfr = *(const bf16x8*)(Wtb + (size_t)((ctbeg + ct) * 16 + r) * 128 + k0);
            acc[ct] = __builtin_amdgcn_mfma_f32_16x16x32_bf16(af, bfr, acc[ct], 0, 0, 0);
        }
    }
#pragma unroll
    for (int ct = 0; ct < 4; ct++) {
        int c = (ctbeg + ct) * 16 + r;
        float b = bt[c];
#pragma unroll
        for (int reg = 0; reg < 4; reg++) {
            int n = row0 + kg * 4 + reg;
            if (n < NN) {
                float z = acc[ct][reg] + b;
                xb[(size_t)n * 128 + c] = bfbitsu(fmaxf(z, 0.f));
            }
        }
    }
}

// -------- fused QKV body, templated on column tile range --------
template<int CTBEG, int NCT>
__device__ __forceinline__ void qkv_body(const ushort* __restrict__ xb,
                                         const ushort* __restrict__ Wqkvb,
                                         const float* __restrict__ bq,
                                         const float* __restrict__ bk,
                                         const float* __restrict__ bv,
                                         float* __restrict__ Qall,
                                         ushort* __restrict__ Kbf,
                                         ushort* __restrict__ Vbf,
                                         int row0, int r, int kg) {
    int ar = row0 + r;
    if (ar > NN - 1) ar = NN - 1;
    f32x4 acc[NCT];
#pragma unroll
    for (int ct = 0; ct < NCT; ct++) acc[ct] = f32x4{0.f, 0.f, 0.f, 0.f};
#pragma unroll
    for (int ks = 0; ks < 4; ks++) {
        int k0 = ks * 32 + kg * 8;
        bf16x8 af = *(const bf16x8*)(xb + (size_t)ar * 128 + k0);
#pragma unroll
        for (int ct = 0; ct < NCT; ct++) {
            bf16x8 bfr = *(const bf16x8*)(Wqkvb + (size_t)((CTBEG + ct) * 16 + r) * 128 + k0);
            acc[ct] = __builtin_amdgcn_mfma_f32_16x16x32_bf16(af, bfr, acc[ct], 0, 0, 0);
        }
    }
#pragma unroll
    for (int ct = 0; ct < NCT; ct++) {
        int c = (CTBEG + ct) * 16 + r;
        float bias;
        if (c < 128) bias = bq[c];
        else if (c < 256) bias = bk[c - 128];
        else { int cv = c - 256; bias = (cv < 40) ? bv[cv] : 0.f; }
#pragma unroll
        for (int reg = 0; reg < 4; reg++) {
            int n = row0 + kg * 4 + reg;
            if (n >= NN) continue;
            float z = acc[ct][reg] + bias;
            if (c < 128) {
                float q = z > 0.f ? 1.f + z : __expf(z);
                Qall[(size_t)(c >> 5) * NN * 32 + (size_t)n * 32 + (c & 31)] = q;
            } else if (c < 256) {
                int cc = c - 128;
                float kv = z > 0.f ? 1.f + z : __expf(z);
                Kbf[(size_t)(cc >> 5) * NN * 32 + (size_t)n * 32 + (cc & 31)] = bfbitsu(kv);
            } else {
                int cv = c - 256;
                if (cv < 40) {
                    int hh = cv / 10, cc = cv - hh * 10;
                    Vbf[(size_t)n * 64 + hh * 16 + cc] = bfbitsu(z);
                }
            }
        }
    }
}

__global__ __launch_bounds__(256) void qkv_kernel(const ushort* __restrict__ xb,
                                                  const ushort* __restrict__ Wqkvb,
                                                  const float* __restrict__ bq,
                                                  const float* __restrict__ bk,
                                                  const float* __restrict__ bv,
                                                  float* __restrict__ Qall,
                                                  ushort* __restrict__ Kbf,
                                                  ushort* __restrict__ Vbf) {
    int wid = threadIdx.x >> 6, lane = threadIdx.x & 63;
    int row0 = blockIdx.x * 64 + wid * 16;
    int r = lane & 15, kg = lane >> 4;
    if (blockIdx.y == 0)
        qkv_body<0, 8>(xb, Wqkvb, bq, bk, bv, Qall, Kbf, Vbf, row0, r, kg);
    else if (blockIdx.y == 1)
        qkv_body<8, 8>(xb, Wqkvb, bq, bk, bv, Qall, Kbf, Vbf, row0, r, kg);
    else
        qkv_body<16, 3>(xb, Wqkvb, bq, bk, bv, Qall, Kbf, Vbf, row0, r, kg);
}

// -------- out init: out[n,c] = hopwise[0] * sum_h V[n,h,c] --------
__global__ void vinit_kernel(float* __restrict__ out, const ushort* __restrict__ Vbf,
                             const float* __restrict__ hopwise) {
    int idx = blockIdx.x * blockDim.x + threadIdx.x;
    if (idx >= NN * NC) return;
    int n = idx / NC, c = idx - n * NC;
    const ushort* v = Vbf + (size_t)n * 64 + c;
    out[idx] = hopwise[0] * (bfs(v[0]) + bfs(v[16]) + bfs(v[32]) + bfs(v[48]));
}

// -------- shared epilog --------
__device__ __forceinline__ void hop_epilog(float acc[10], float kacc, int gw, int lane, int i,
                                           const float* __restrict__ Qall_h,
                                           float* __restrict__ out,
                                           uint4* __restrict__ Mqn, uint* __restrict__ Mrn,
                                           ushort* __restrict__ Knext,
                                           const float* __restrict__ hopwise,
                                           const float* __restrict__ headwise,
                                           int h, int hop, int write_next) {
#pragma unroll
    for (int c = 0; c < 10; c++) acc[c] += __shfl_xor(acc[c], 32);
    kacc += __shfl_xor(kacc, 32);

    float q = Qall_h[(size_t)gw * 32 + i];
    float num[10];
#pragma unroll
    for (int c = 0; c < 10; c++) num[c] = q * acc[c];
    float den = q * kacc;
#pragma unroll
    for (int off = 16; off >= 1; off >>= 1) {
#pragma unroll
        for (int c = 0; c < 10; c++) num[c] += __shfl_xor(num[c], off);
        den += __shfl_xor(den, off);
    }
    float e0 = __expf(headwise[0 * KHOPS + hop]);
    float e1 = __expf(headwise[1 * KHOPS + hop]);
    float e2 = __expf(headwise[2 * KHOPS + hop]);
    float e3 = __expf(headwise[3 * KHOPS + hop]);
    float eh = (h == 0) ? e0 : (h == 1) ? e1 : (h == 2) ? e2 : e3;
    float gamma = hopwise[hop + 1] * eh / (e0 + e1 + e2 + e3);
    float scale = gamma / (den + 1e-5f);
    if (lane < 10) {
        float v = lane == 0 ? num[0] : lane == 1 ? num[1] : lane == 2 ? num[2] :
                  lane == 3 ? num[3] : lane == 4 ? num[4] : lane == 5 ? num[5] :
                  lane == 6 ? num[6] : lane == 7 ? num[7] : lane == 8 ? num[8] : num[9];
        out[(size_t)gw * 10 + lane] += v * scale;
    }
    if (write_next && lane < 32) {
        uint4 o;
        o.x = packbf(acc[0], acc[1]);
        o.y = packbf(acc[2], acc[3]);
        o.z = packbf(acc[4], acc[5]);
        o.w = packbf(acc[6], acc[7]);
        Mqn[(size_t)gw * 32 + i] = o;
        Mrn[(size_t)gw * 32 + i] = packbf(acc[8], acc[9]);
        Knext[(size_t)gw * 32 + i] = bfbitsu(kacc);
    }
}

// -------- edge accumulate helpers --------
__device__ __forceinline__ void macc(float acc[10], float& kacc, uint4 q, uint rr, float kv) {
    kacc += kv;
    acc[0] += bflo(q.x); acc[1] += bfhi(q.x);
    acc[2] += bflo(q.y); acc[3] += bfhi(q.y);
    acc[4] += bflo(q.z); acc[5] += bfhi(q.z);
    acc[6] += bflo(q.w); acc[7] += bfhi(q.w);
    acc[8] += bflo(rr);  acc[9] += bfhi(rr);
}
__device__ __forceinline__ void vacc(float acc[10], float& kacc, uint4 v4, uint v1, float kv) {
    kacc += kv;
    acc[0] += kv * bflo(v4.x); acc[1] += kv * bfhi(v4.x);
    acc[2] += kv * bflo(v4.y); acc[3] += kv * bfhi(v4.y);
    acc[4] += kv * bflo(v4.z); acc[5] += kv * bfhi(v4.z);
    acc[6] += kv * bflo(v4.w); acc[7] += kv * bfhi(v4.w);
    acc[8] += kv * bflo(v1);   acc[9] += kv * bfhi(v1);
}

// -------- hop 0: gather bf16 K,V; outer-product in registers --------
__global__ __launch_bounds__(256) void agg0_kernel(const ushort* __restrict__ Kbf,
                                                   const ushort* __restrict__ Vbf,
                                                   const float* __restrict__ Qall,
                                                   float* __restrict__ out,
                                                   uint4* __restrict__ Mqn, uint* __restrict__ Mrn,
                                                   ushort* __restrict__ Knext,
                                                   const int* __restrict__ rowptr,
                                                   const int* __restrict__ srows,
                                                   const float* __restrict__ hopwise,
                                                   const float* __restrict__ headwise,
                                                   int h) {
    int gw = (blockIdx.x * 256 + threadIdx.x) >> 6;
    int lane = threadIdx.x & 63;
    int half = lane >> 5, i = lane & 31;
    int beg = rowptr[gw], end = rowptr[gw + 1];
    const ushort* Kh = Kbf + (size_t)h * NN * 32;
    float acc[10] = {0.f, 0.f, 0.f, 0.f, 0.f, 0.f, 0.f, 0.f, 0.f, 0.f};
    float kacc = 0.f;
    int e = beg + half;
    for (; e + 6 < end; e += 8) {
        int s0 = srows[e], s1 = srows[e + 2], s2 = srows[e + 4], s3 = srows[e + 6];
        float k0 = bfs(Kh[(size_t)s0 * 32 + i]);
        float k1 = bfs(Kh[(size_t)s1 * 32 + i]);
        float k2 = bfs(Kh[(size_t)s2 * 32 + i]);
        float k3 = bfs(Kh[(size_t)s3 * 32 + i]);
        const ushort* v0 = Vbf + (size_t)s0 * 64 + h * 16;
        const ushort* v1 = Vbf + (size_t)s1 * 64 + h * 16;
        const ushort* v2 = Vbf + (size_t)s2 * 64 + h * 16;
        const ushort* v3 = Vbf + (size_t)s3 * 64 + h * 16;
        uint4 a = *(const uint4*)v0; uint ar1 = *(const uint*)(v0 + 8);
        uint4 b = *(const uint4*)v1; uint br = *(const uint*)(v1 + 8);
        uint4 c = *(const uint4*)v2; uint cr = *(const uint*)(v2 + 8);
        uint4 d = *(const uint4*)v3; uint dr = *(const uint*)(v3 + 8);
        vacc(acc, kacc, a, ar1, k0);
        vacc(acc, kacc, b, br, k1);
        vacc(acc, kacc, c, cr, k2);
        vacc(acc, kacc, d, dr, k3);
    }
    for (; e < end; e += 2) {
        int src = srows[e];
        float kv = bfs(Kh[(size_t)src * 32 + i]);
        const ushort* vb = Vbf + (size_t)src * 64 + h * 16;
        uint4 a = *(const uint4*)vb;
        uint ar1 = *(const uint*)(vb + 8);
        vacc(acc, kacc, a, ar1, kv);
    }
    hop_epilog(acc, kacc, gw, lane, i, Qall + (size_t)h * NN * 32, out, Mqn, Mrn, Knext,
               hopwise, headwise, h, 0, 1);
}

// -------- hops >=1: gather bf16 M (uint4 + uint), K --------
__global__ __launch_bounds__(256) void agg_kernel(const uint4* __restrict__ Mq,
                                                  const uint* __restrict__ Mr,
                                                  const ushort* __restrict__ Kcur,
                                                  const float* __restrict__ Qall,
                                                  float* __restrict__ out,
                                                  uint4* __restrict__ Mqn, uint* __restrict__ Mrn,
                                                  ushort* __restrict__ Knext,
                                                  const int* __restrict__ rowptr,
                                                  const int* __restrict__ srows,
                                                  const float* __restrict__ hopwise,
                                                  const float* __restrict__ headwise,
                                                  int h, int hop, int write_next) {
    int gw = (blockIdx.x * 256 + threadIdx.x) >> 6;
    int lane = threadIdx.x & 63;
    int half = lane >> 5, i = lane & 31;
    int beg = rowptr[gw], end = rowptr[gw + 1];
    float acc[10] = {0.f, 0.f, 0.f, 0.f, 0.f, 0.f, 0.f, 0.f, 0.f, 0.f};
    float kacc = 0.f;
    int e = beg + half;
    for (; e + 6 < end; e += 8) {
        int s0 = srows[e], s1 = srows[e + 2], s2 = srows[e + 4], s3 = srows[e + 6];
        uint4 a = Mq[(size_t)s0 * 32 + i];
        uint4 b = Mq[(size_t)s1 * 32 + i];
        uint4 c = Mq[(size_t)s2 * 32 + i];
        uint4 d = Mq[(size_t)s3 * 32 + i];
        uint ar1 = Mr[(size_t)s0 * 32 + i];
        uint br = Mr[(size_t)s1 * 32 + i];
        uint cr = Mr[(size_t)s2 * 32 + i];
        uint dr = Mr[(size_t)s3 * 32 + i];
        float k0 = bfs(Kcur[(size_t)s0 * 32 + i]);
        float k1 = bfs(Kcur[(size_t)s1 * 32 + i]);
        float k2 = bfs(Kcur[(size_t)s2 * 32 + i]);
        float k3 = bfs(Kcur[(size_t)s3 * 32 + i]);
        macc(acc, kacc, a, ar1, k0);
        macc(acc, kacc, b, br, k1);
        macc(acc, kacc, c, cr, k2);
        macc(acc, kacc, d, dr, k3);
    }
    for (; e < end; e += 2) {
        int src = srows[e];
        macc(acc, kacc, Mq[(size_t)src * 32 + i], Mr[(size_t)src * 32 + i],
             bfs(Kcur[(size_t)src * 32 + i]));
    }
    hop_epilog(acc, kacc, gw, lane, i, Qall + (size_t)h * NN * 32, out, Mqn, Mrn, Knext,
               hopwise, headwise, h, hop, write_next);
}

extern "C" void kernel_launch(void* const* d_in, const int* in_sizes, int n_in,
                              void* d_out, int out_size, void* d_ws, size_t ws_size,
                              hipStream_t stream) {
    const float* nf = (const float*)d_in[0];
    const int* ei = (const int*)d_in[1];
    const float* Wt = (const float*)d_in[2];
    const float* bt = (const float*)d_in[3];
    const float* Wq = (const float*)d_in[4];
    const float* bq = (const float*)d_in[5];
    const float* Wk = (const float*)d_in[6];
    const float* bk = (const float*)d_in[7];
    const float* Wv = (const float*)d_in[8];
    const float* bv = (const float*)d_in[9];
    const float* hopwise = (const float*)d_in[10];
    const float* headwise = (const float*)d_in[11];
    float* out = (float*)d_out;

    char* p = (char*)d_ws;
    auto alloc = [&](size_t bytes) {
        char* r = p;
        p += (bytes + 255) & ~(size_t)255;
        return r;
    };
    int* rowptr = (int*)alloc((NN + 4) * sizeof(int));
    int* cursor = (int*)alloc((NN + 4) * sizeof(int));
    int* bsum = (int*)alloc(NBLK * sizeof(int));
    int* boff = (int*)alloc(NBLK * sizeof(int));
    int* srows = (int*)alloc((size_t)NE * sizeof(int));
    int* flag = (int*)alloc(sizeof(int));
    ushort* Wtb = (ushort*)alloc(128 * 128 * sizeof(ushort));
    ushort* Wqkvb = (ushort*)alloc(304 * 128 * sizeof(ushort));
    ushort* xb = (ushort*)alloc((size_t)NN * 128 * sizeof(ushort));
    float* Qall = (float*)alloc((size_t)NH * NN * HC * sizeof(float));
    ushort* Kbf = (ushort*)alloc((size_t)NH * NN * HC * sizeof(ushort));
    ushort* Vbf = (ushort*)alloc((size_t)NN * 64 * sizeof(ushort));
    uint4* Mqa = (uint4*)alloc((size_t)NN * 32 * sizeof(uint4));
    uint4* Mqb = (uint4*)alloc((size_t)NN * 32 * sizeof(uint4));
    uint* Mra = (uint*)alloc((size_t)NN * 32 * sizeof(uint));
    uint* Mrb = (uint*)alloc((size_t)NN * 32 * sizeof(uint));
    ushort* Ka = (ushort*)alloc((size_t)NN * 32 * sizeof(ushort));
    ushort* Kb = (ushort*)alloc((size_t)NN * 32 * sizeof(ushort));

    detect_kernel<<<1, 64, 0, stream>>>(ei, flag);
    zero_kernel<<<(NN + 255) / 256, 256, 0, stream>>>(cursor, NN);
    hist_kernel<<<(NE + 255) / 256, 256, 0, stream>>>(ei, flag, cursor);
    bsum_kernel<<<NBLK, 256, 0, stream>>>(cursor, bsum);
    bscan_kernel<<<1, 64, 0, stream>>>(bsum, boff, rowptr);
    scanb_kernel<<<NBLK, 256, 0, stream>>>(cursor, boff, rowptr, cursor);
    scatter_kernel<<<(NE + 255) / 256, 256, 0, stream>>>(ei, flag, cursor, srows);

    wconv_kernel<<<(304 * 128 + 255) / 256, 256, 0, stream>>>(Wt, Wq, Wk, Wv, Wtb, Wqkvb);
    int nrb = (NN + 63) / 64;
    xm_kernel<<<dim3(nrb, 2), 256, 0, stream>>>(nf, Wtb, bt, xb);
    qkv_kernel<<<dim3(nrb, 3), 256, 0, stream>>>(xb, Wqkvb, bq, bk, bv, Qall, Kbf, Vbf);
    vinit_kernel<<<(NN * NC + 255) / 256, 256, 0, stream>>>(out, Vbf, hopwise);

    for (int h = 0; h < NH; h++) {
        agg0_kernel<<<NN / 4, 256, 0, stream>>>(Kbf, Vbf, Qall, out, Mqa, Mra, Ka,
                                                rowptr, srows, hopwise, headwise, h);
        agg_kernel<<<NN / 4, 256, 0, stream>>>(Mqa, Mra, Ka, Qall, out, Mqb, Mrb, Kb,
                                               rowptr, srows, hopwise, headwise, h, 1, 1);
        agg_kernel<<<NN / 4, 256, 0, stream>>>(Mqb, Mrb, Kb, Qall, out, Mqa, Mra, Ka,
                                               rowptr, srows, hopwise, headwise, h, 2, 0);
    }
}

// Round 7
// 391.082 us; speedup vs baseline: 5.0039x; 1.7287x over previous
//
#include <hip/hip_runtime.h>
#include <hip/hip_bf16.h>

#define NN 50000
#define NE 400000
#define NF 128
#define HID 128
#define NH 4
#define HC 32
#define NC 10
#define KHOPS 3
#define NBLK ((NN + 1023) / 1024)   // 49

typedef unsigned int uint;
typedef unsigned short ushort;
typedef __attribute__((ext_vector_type(8))) short bf16x8;
typedef __attribute__((ext_vector_type(4))) float f32x4;
typedef __attribute__((ext_vector_type(2))) float f32x2;

// -------- edge dtype detect: int64 (odd words all zero) vs int32 --------
__global__ void detect_kernel(const int* __restrict__ ei, int* __restrict__ flag) {
    int w = ei[2 * threadIdx.x + 1];
    unsigned long long b = __ballot(w != 0);
    if (threadIdx.x == 0) *flag = (b == 0ULL) ? 1 : 0;  // 1 => int64
}

__device__ __forceinline__ int edge_row(const int* ei, int is64, int e) {
    return is64 ? ei[2 * e] : ei[e];
}
__device__ __forceinline__ int edge_col(const int* ei, int is64, int e) {
    return is64 ? ei[2 * NE + 2 * e] : ei[NE + e];
}

__global__ void zero_kernel(int* __restrict__ p, int n) {
    int i = blockIdx.x * blockDim.x + threadIdx.x;
    if (i < n) p[i] = 0;
}

__global__ void hist_kernel(const int* __restrict__ ei, const int* __restrict__ flag,
                            int* __restrict__ counts) {
    int e = blockIdx.x * blockDim.x + threadIdx.x;
    if (e >= NE) return;
    int c = edge_col(ei, *flag, e);
    atomicAdd(&counts[c], 1);
}

// ---- hierarchical scan ----
__global__ __launch_bounds__(256) void bsum_kernel(const int* __restrict__ counts,
                                                   int* __restrict__ bsum) {
    int b = blockIdx.x, tid = threadIdx.x;
    int base = b * 1024 + tid * 4;
    int4 v = {0, 0, 0, 0};
    if (base < NN) v = *(const int4*)(counts + base);
    int s = v.x + v.y + v.z + v.w;
#pragma unroll
    for (int off = 32; off >= 1; off >>= 1) s += __shfl_xor(s, off);
    __shared__ int ws[4];
    int lane = tid & 63, w = tid >> 6;
    if (lane == 0) ws[w] = s;
    __syncthreads();
    if (tid == 0) bsum[b] = ws[0] + ws[1] + ws[2] + ws[3];
}

__global__ void bscan_kernel(const int* __restrict__ bsum, int* __restrict__ boff,
                             int* __restrict__ rowptr) {
    int lane = threadIdx.x;
    int v = (lane < NBLK) ? bsum[lane] : 0;
    int t = v;
#pragma unroll
    for (int off = 1; off < 64; off <<= 1) {
        int u = __shfl_up(t, off);
        if (lane >= off) t += u;
    }
    if (lane < NBLK) boff[lane] = t - v;
    if (lane == NBLK - 1) rowptr[NN] = t;
}

__global__ __launch_bounds__(256) void scanb_kernel(const int* __restrict__ counts,
                                                    const int* __restrict__ boff,
                                                    int* __restrict__ rowptr,
                                                    int* __restrict__ cursor) {
    int b = blockIdx.x, tid = threadIdx.x;
    int base = b * 1024 + tid * 4;
    int4 v = {0, 0, 0, 0};
    if (base < NN) v = *(const int4*)(counts + base);
    int s3 = v.x + v.y + v.z + v.w;
    int lane = tid & 63, w = tid >> 6;
    int t = s3;
#pragma unroll
    for (int off = 1; off < 64; off <<= 1) {
        int u = __shfl_up(t, off);
        if (lane >= off) t += u;
    }
    __shared__ int ws[4];
    if (lane == 63) ws[w] = t;
    __syncthreads();
    int wofs = boff[b];
    for (int i = 0; i < 4; i++) wofs += (i < w) ? ws[i] : 0;
    int excl = wofs + t - s3;
    if (base < NN) {
        int4 o;
        o.x = excl;
        o.y = excl + v.x;
        o.z = o.y + v.y;
        o.w = o.z + v.z;
        *(int4*)(rowptr + base) = o;
        *(int4*)(cursor + base) = o;
    }
}

__global__ void scatter_kernel(const int* __restrict__ ei, const int* __restrict__ flag,
                               int* __restrict__ cursor, int* __restrict__ srows) {
    int e = blockIdx.x * blockDim.x + threadIdx.x;
    if (e >= NE) return;
    int is64 = *flag;
    int r = edge_row(ei, is64, e);
    int c = edge_col(ei, is64, e);
    int pos = atomicAdd(&cursor[c], 1);
    srows[pos] = r;
}

// -------- bf16 helpers --------
__device__ __forceinline__ short bfbits(float f) {
    __hip_bfloat16 h = __float2bfloat16(f);
    return *reinterpret_cast<short*>(&h);
}
__device__ __forceinline__ ushort bfbitsu(float f) {
    __hip_bfloat16 h = __float2bfloat16(f);
    return *reinterpret_cast<ushort*>(&h);
}
__device__ __forceinline__ float bflo(uint u) { return __uint_as_float(u << 16); }
__device__ __forceinline__ float bfhi(uint u) { return __uint_as_float(u & 0xFFFF0000u); }
__device__ __forceinline__ float bfs(ushort u) { return __uint_as_float(((uint)u) << 16); }

// -------- fp8 e4m3 pack/unpack (HW cvt; word-select must be compile-time) --------
template<bool HI>
__device__ __forceinline__ uint pk8(float a, float b, uint old) {
    return __builtin_amdgcn_cvt_pk_fp8_f32(a, b, old, HI);
}
template<bool HI>
__device__ __forceinline__ f32x2 upk8(uint w) {
    return __builtin_amdgcn_cvt_pk_f32_fp8(w, HI);
}

// -------- weight convert: bf16, transposed [col][k] --------
__global__ void wconv_kernel(const float* __restrict__ Wt, const float* __restrict__ Wq,
                             const float* __restrict__ Wk, const float* __restrict__ Wv,
                             ushort* __restrict__ Wtb, ushort* __restrict__ Wqkvb) {
    int idx = blockIdx.x * 256 + threadIdx.x;
    if (idx < 128 * 128) {
        int c = idx >> 7, k = idx & 127;
        Wtb[c * 128 + k] = bfbitsu(Wt[k * 128 + c]);
    }
    if (idx < 304 * 128) {
        int c = idx >> 7, k = idx & 127;
        float w;
        if (c < 128) w = Wq[k * 128 + c];
        else if (c < 256) w = Wk[k * 128 + (c - 128)];
        else { int cv = c - 256; w = (cv < 40) ? Wv[k * 40 + cv] : 0.f; }
        Wqkvb[c * 128 + k] = bfbitsu(w);
    }
}

// -------- x = relu(nf @ Wt + bt), MFMA, column-split over gridDim.y --------
__global__ __launch_bounds__(256) void xm_kernel(const float* __restrict__ nf,
                                                 const ushort* __restrict__ Wtb,
                                                 const float* __restrict__ bt,
                                                 ushort* __restrict__ xb) {
    int wid = threadIdx.x >> 6, lane = threadIdx.x & 63;
    int row0 = blockIdx.x * 64 + wid * 16;
    int r = lane & 15, kg = lane >> 4;
    int ar = row0 + r;
    if (ar > NN - 1) ar = NN - 1;
    int ctbeg = blockIdx.y * 4;
    f32x4 acc[4];
#pragma unroll
    for (int ct = 0; ct < 4; ct++) acc[ct] = f32x4{0.f, 0.f, 0.f, 0.f};
#pragma unroll
    for (int ks = 0; ks < 4; ks++) {
        int k0 = ks * 32 + kg * 8;
        const float4* ap = (const float4*)(nf + (size_t)ar * 128 + k0);
        float4 a0 = ap[0], a1 = ap[1];
        bf16x8 af;
        af[0] = bfbits(a0.x); af[1] = bfbits(a0.y); af[2] = bfbits(a0.z); af[3] = bfbits(a0.w);
        af[4] = bfbits(a1.x); af[5] = bfbits(a1.y); af[6] = bfbits(a1.z); af[7] = bfbits(a1.w);
#pragma unroll
        for (int ct = 0; ct < 4; ct++) {
            bf16x8 bfr = *(const bf16x8*)(Wtb + (size_t)((ctbeg + ct) * 16 + r) * 128 + k0);
            acc[ct] = __builtin_amdgcn_mfma_f32_16x16x32_bf16(af, bfr, acc[ct], 0, 0, 0);
        }
    }
#pragma unroll
    for (int ct = 0; ct < 4; ct++) {
        int c = (ctbeg + ct) * 16 + r;
        float b = bt[c];
#pragma unroll
        for (int reg = 0; reg < 4; reg++) {
            int n = row0 + kg * 4 + reg;
            if (n < NN) {
                float z = acc[ct][reg] + b;
                xb[(size_t)n * 128 + c] = bfbitsu(fmaxf(z, 0.f));
            }
        }
    }
}

// -------- fused QKV body; Q -> Qp[n][128] f32, K -> Kpp[n][128] bf16, V -> Vbf[n][4][16] --------
template<int CTBEG, int NCT>
__device__ __forceinline__ void qkv_body(const ushort* __restrict__ xb,
                                         const ushort* __restrict__ Wqkvb,
                                         const float* __restrict__ bq,
                                         const float* __restrict__ bk,
                                         const float* __restrict__ bv,
                                         float* __restrict__ Qp,
                                         ushort* __restrict__ Kpp,
                                         ushort* __restrict__ Vbf,
                                         int row0, int r, int kg) {
    int ar = row0 + r;
    if (ar > NN - 1) ar = NN - 1;
    f32x4 acc[NCT];
#pragma unroll
    for (int ct = 0; ct < NCT; ct++) acc[ct] = f32x4{0.f, 0.f, 0.f, 0.f};
#pragma unroll
    for (int ks = 0; ks < 4; ks++) {
        int k0 = ks * 32 + kg * 8;
        bf16x8 af = *(const bf16x8*)(xb + (size_t)ar * 128 + k0);
#pragma unroll
        for (int ct = 0; ct < NCT; ct++) {
            bf16x8 bfr = *(const bf16x8*)(Wqkvb + (size_t)((CTBEG + ct) * 16 + r) * 128 + k0);
            acc[ct] = __builtin_amdgcn_mfma_f32_16x16x32_bf16(af, bfr, acc[ct], 0, 0, 0);
        }
    }
#pragma unroll
    for (int ct = 0; ct < NCT; ct++) {
        int c = (CTBEG + ct) * 16 + r;
        float bias;
        if (c < 128) bias = bq[c];
        else if (c < 256) bias = bk[c - 128];
        else { int cv = c - 256; bias = (cv < 40) ? bv[cv] : 0.f; }
#pragma unroll
        for (int reg = 0; reg < 4; reg++) {
            int n = row0 + kg * 4 + reg;
            if (n >= NN) continue;
            float z = acc[ct][reg] + bias;
            if (c < 128) {
                float q = z > 0.f ? 1.f + z : __expf(z);
                Qp[(size_t)n * 128 + c] = q;
            } else if (c < 256) {
                int cc = c - 128;
                float kv = z > 0.f ? 1.f + z : __expf(z);
                Kpp[(size_t)n * 128 + cc] = bfbitsu(kv);
            } else {
                int cv = c - 256;
                if (cv < 40) {
                    int hh = cv / 10, cc = cv - hh * 10;
                    Vbf[(size_t)n * 64 + hh * 16 + cc] = bfbitsu(z);
                }
            }
        }
    }
}

__global__ __launch_bounds__(256) void qkv_kernel(const ushort* __restrict__ xb,
                                                  const ushort* __restrict__ Wqkvb,
                                                  const float* __restrict__ bq,
                                                  const float* __restrict__ bk,
                                                  const float* __restrict__ bv,
                                                  float* __restrict__ Qp,
                                                  ushort* __restrict__ Kpp,
                                                  ushort* __restrict__ Vbf) {
    int wid = threadIdx.x >> 6, lane = threadIdx.x & 63;
    int row0 = blockIdx.x * 64 + wid * 16;
    int r = lane & 15, kg = lane >> 4;
    if (blockIdx.y == 0)
        qkv_body<0, 8>(xb, Wqkvb, bq, bk, bv, Qp, Kpp, Vbf, row0, r, kg);
    else if (blockIdx.y == 1)
        qkv_body<8, 8>(xb, Wqkvb, bq, bk, bv, Qp, Kpp, Vbf, row0, r, kg);
    else
        qkv_body<16, 3>(xb, Wqkvb, bq, bk, bv, Qp, Kpp, Vbf, row0, r, kg);
}

// -------- out init: out[n,c] = hopwise[0] * sum_h V[n,h,c] --------
__global__ void vinit_kernel(float* __restrict__ out, const ushort* __restrict__ Vbf,
                             const float* __restrict__ hopwise) {
    int idx = blockIdx.x * blockDim.x + threadIdx.x;
    if (idx >= NN * NC) return;
    int n = idx / NC, c = idx - n * NC;
    const ushort* v = Vbf + (size_t)n * 64 + c;
    out[idx] = hopwise[0] * (bfs(v[0]) + bfs(v[16]) + bfs(v[32]) + bfs(v[48]));
}

// -------- fused all-head epilog --------
// lane l owns pairs p0=2l, 2l+1 (head h = l>>4). M is stored fp8 e4m3 at 1/16
// scale: h_scale compensates in the readout, ss scales acc at store time.
__device__ __forceinline__ void fused_epilog(float a0[10], float a1[10], float k0a, float k1a,
                                             int gw, int lane,
                                             const float* __restrict__ Qp,
                                             float* __restrict__ out,
                                             uint4* __restrict__ Mq4n, uint* __restrict__ Mrun,
                                             ushort* __restrict__ Kn,
                                             const float* __restrict__ hopwise,
                                             const float* __restrict__ headwise,
                                             int hop, int write_next,
                                             float h_scale, float ss) {
    int p0 = lane * 2;
    float2 q = *(const float2*)(Qp + (size_t)gw * 128 + p0);
    float num[10];
#pragma unroll
    for (int c = 0; c < 10; c++) num[c] = q.x * a0[c] + q.y * a1[c];
    float den = q.x * k0a + q.y * k1a;
#pragma unroll
    for (int off = 8; off >= 1; off >>= 1) {
#pragma unroll
        for (int c = 0; c < 10; c++) num[c] += __shfl_xor(num[c], off);
        den += __shfl_xor(den, off);
    }
    float e0 = __expf(headwise[0 * KHOPS + hop]);
    float e1 = __expf(headwise[1 * KHOPS + hop]);
    float e2 = __expf(headwise[2 * KHOPS + hop]);
    float e3 = __expf(headwise[3 * KHOPS + hop]);
    int h = lane >> 4;
    float eh = (h == 0) ? e0 : (h == 1) ? e1 : (h == 2) ? e2 : e3;
    float gamma = hopwise[hop + 1] * eh / (e0 + e1 + e2 + e3);
    float s = h_scale * gamma / (den + 1e-5f);
    float tot[10];
#pragma unroll
    for (int c = 0; c < 10; c++) {
        tot[c] = s * num[c];
        tot[c] += __shfl_xor(tot[c], 16);
        tot[c] += __shfl_xor(tot[c], 32);
    }
    if (lane < 10) {
        float v = lane == 0 ? tot[0] : lane == 1 ? tot[1] : lane == 2 ? tot[2] :
                  lane == 3 ? tot[3] : lane == 4 ? tot[4] : lane == 5 ? tot[5] :
                  lane == 6 ? tot[6] : lane == 7 ? tot[7] : lane == 8 ? tot[8] : tot[9];
        out[(size_t)gw * 10 + lane] += v;
    }
    if (write_next) {
        uint4 o;
        uint x = pk8<false>(a0[0] * ss, a0[1] * ss, 0u);
        o.x = pk8<true>(a0[2] * ss, a0[3] * ss, x);
        x = pk8<false>(a0[4] * ss, a0[5] * ss, 0u);
        o.y = pk8<true>(a0[6] * ss, a0[7] * ss, x);
        x = pk8<false>(a1[0] * ss, a1[1] * ss, 0u);
        o.z = pk8<true>(a1[2] * ss, a1[3] * ss, x);
        x = pk8<false>(a1[4] * ss, a1[5] * ss, 0u);
        o.w = pk8<true>(a1[6] * ss, a1[7] * ss, x);
        Mq4n[(size_t)gw * 64 + lane] = o;
        x = pk8<false>(a0[8] * ss, a0[9] * ss, 0u);
        x = pk8<true>(a1[8] * ss, a1[9] * ss, x);
        Mrun[(size_t)gw * 64 + lane] = x;
        uint kw = (uint)bfbitsu(k0a) | (((uint)bfbitsu(k1a)) << 16);
        *(uint*)(Kn + (size_t)gw * 128 + p0) = kw;
    }
}

// -------- per-edge fp8 accumulate --------
__device__ __forceinline__ void edge_acc(float a0[10], float a1[10], float& k0a, float& k1a,
                                         uint4 mq, uint mr, uint kk) {
    f32x2 f;
    f = upk8<false>(mq.x); a0[0] += f.x; a0[1] += f.y;
    f = upk8<true>(mq.x);  a0[2] += f.x; a0[3] += f.y;
    f = upk8<false>(mq.y); a0[4] += f.x; a0[5] += f.y;
    f = upk8<true>(mq.y);  a0[6] += f.x; a0[7] += f.y;
    f = upk8<false>(mq.z); a1[0] += f.x; a1[1] += f.y;
    f = upk8<true>(mq.z);  a1[2] += f.x; a1[3] += f.y;
    f = upk8<false>(mq.w); a1[4] += f.x; a1[5] += f.y;
    f = upk8<true>(mq.w);  a1[6] += f.x; a1[7] += f.y;
    f = upk8<false>(mr);   a0[8] += f.x; a0[9] += f.y;
    f = upk8<true>(mr);    a1[8] += f.x; a1[9] += f.y;
    k0a += bflo(kk);
    k1a += bfhi(kk);
}

// -------- fused hop 0: all heads; gather bf16 K row + per-head V row --------
__global__ __launch_bounds__(256) void aggf0_kernel(const ushort* __restrict__ Kpp,
                                                    const ushort* __restrict__ Vbf,
                                                    const float* __restrict__ Qp,
                                                    float* __restrict__ out,
                                                    uint4* __restrict__ Mq4n, uint* __restrict__ Mrun,
                                                    ushort* __restrict__ Kn,
                                                    const int* __restrict__ rowptr,
                                                    const int* __restrict__ srows,
                                                    const float* __restrict__ hopwise,
                                                    const float* __restrict__ headwise) {
    int gw = (blockIdx.x * 256 + threadIdx.x) >> 6;
    int lane = threadIdx.x & 63;
    int p0 = lane * 2;
    int h = lane >> 4;
    int beg = rowptr[gw], end = rowptr[gw + 1];
    float a0[10] = {0.f}, a1[10] = {0.f};
    float k0a = 0.f, k1a = 0.f;
    int e = beg;
    for (; e + 1 < end; e += 2) {
        int s0 = srows[e], s1 = srows[e + 1];
        uint kk0 = *(const uint*)(Kpp + (size_t)s0 * 128 + p0);
        uint kk1 = *(const uint*)(Kpp + (size_t)s1 * 128 + p0);
        const ushort* vb0 = Vbf + (size_t)s0 * 64 + h * 16;
        const ushort* vb1 = Vbf + (size_t)s1 * 64 + h * 16;
        uint4 v40 = *(const uint4*)vb0; uint v10 = *(const uint*)(vb0 + 8);
        uint4 v41 = *(const uint4*)vb1; uint v11 = *(const uint*)(vb1 + 8);
        float k00 = bflo(kk0), k01 = bfhi(kk0);
        float k10 = bflo(kk1), k11 = bfhi(kk1);
        k0a += k00 + k10; k1a += k01 + k11;
        float vv0[10] = {bflo(v40.x), bfhi(v40.x), bflo(v40.y), bfhi(v40.y), bflo(v40.z),
                         bfhi(v40.z), bflo(v40.w), bfhi(v40.w), bflo(v10), bfhi(v10)};
        float vv1[10] = {bflo(v41.x), bfhi(v41.x), bflo(v41.y), bfhi(v41.y), bflo(v41.z),
                         bfhi(v41.z), bflo(v41.w), bfhi(v41.w), bflo(v11), bfhi(v11)};
#pragma unroll
        for (int c = 0; c < 10; c++) {
            a0[c] += k00 * vv0[c] + k10 * vv1[c];
            a1[c] += k01 * vv0[c] + k11 * vv1[c];
        }
    }
    for (; e < end; ++e) {
        int s0 = srows[e];
        uint kk0 = *(const uint*)(Kpp + (size_t)s0 * 128 + p0);
        const ushort* vb0 = Vbf + (size_t)s0 * 64 + h * 16;
        uint4 v40 = *(const uint4*)vb0; uint v10 = *(const uint*)(vb0 + 8);
        float k00 = bflo(kk0), k01 = bfhi(kk0);
        k0a += k00; k1a += k01;
        float vv0[10] = {bflo(v40.x), bfhi(v40.x), bflo(v40.y), bfhi(v40.y), bflo(v40.z),
                         bfhi(v40.z), bflo(v40.w), bfhi(v40.w), bflo(v10), bfhi(v10)};
#pragma unroll
        for (int c = 0; c < 10; c++) {
            a0[c] += k00 * vv0[c];
            a1[c] += k01 * vv0[c];
        }
    }
    // hop0: acc is true M1 -> h_scale=1; store M1/16
    fused_epilog(a0, a1, k0a, k1a, gw, lane, Qp, out, Mq4n, Mrun, Kn,
                 hopwise, headwise, 0, 1, 1.0f, 0.0625f);
}

// -------- fused hops >=1: all heads; per edge uint4 + uint + uint (fp8 M) --------
__global__ __launch_bounds__(256) void aggf_kernel(const uint4* __restrict__ Mq4,
                                                   const uint* __restrict__ Mru,
                                                   const ushort* __restrict__ Kc,
                                                   const float* __restrict__ Qp,
                                                   float* __restrict__ out,
                                                   uint4* __restrict__ Mq4n, uint* __restrict__ Mrun,
                                                   ushort* __restrict__ Kn,
                                                   const int* __restrict__ rowptr,
                                                   const int* __restrict__ srows,
                                                   const float* __restrict__ hopwise,
                                                   const float* __restrict__ headwise,
                                                   int hop, int write_next) {
    int gw = (blockIdx.x * 256 + threadIdx.x) >> 6;
    int lane = threadIdx.x & 63;
    const uint* Kcu = (const uint*)Kc;
    int beg = rowptr[gw], end = rowptr[gw + 1];
    float a0[10] = {0.f}, a1[10] = {0.f};
    float k0a = 0.f, k1a = 0.f;
    int e = beg;
    for (; e + 3 < end; e += 4) {
        int s0 = srows[e], s1 = srows[e + 1], s2 = srows[e + 2], s3 = srows[e + 3];
        uint4 m0 = Mq4[(size_t)s0 * 64 + lane];
        uint4 m1 = Mq4[(size_t)s1 * 64 + lane];
        uint4 m2 = Mq4[(size_t)s2 * 64 + lane];
        uint4 m3 = Mq4[(size_t)s3 * 64 + lane];
        uint r0 = Mru[(size_t)s0 * 64 + lane];
        uint r1 = Mru[(size_t)s1 * 64 + lane];
        uint r2 = Mru[(size_t)s2 * 64 + lane];
        uint r3 = Mru[(size_t)s3 * 64 + lane];
        uint K0 = Kcu[(size_t)s0 * 64 + lane];
        uint K1 = Kcu[(size_t)s1 * 64 + lane];
        uint K2 = Kcu[(size_t)s2 * 64 + lane];
        uint K3 = Kcu[(size_t)s3 * 64 + lane];
        edge_acc(a0, a1, k0a, k1a, m0, r0, K0);
        edge_acc(a0, a1, k0a, k1a, m1, r1, K1);
        edge_acc(a0, a1, k0a, k1a, m2, r2, K2);
        edge_acc(a0, a1, k0a, k1a, m3, r3, K3);
    }
    for (; e < end; ++e) {
        int s0 = srows[e];
        uint4 m0 = Mq4[(size_t)s0 * 64 + lane];
        uint r0 = Mru[(size_t)s0 * 64 + lane];
        uint K0 = Kcu[(size_t)s0 * 64 + lane];
        edge_acc(a0, a1, k0a, k1a, m0, r0, K0);
    }
    // hops>=1: acc is M_{hop+1}/16 -> h_scale=16; store acc as-is (already /16)
    fused_epilog(a0, a1, k0a, k1a, gw, lane, Qp, out, Mq4n, Mrun, Kn,
                 hopwise, headwise, hop, write_next, 16.0f, 1.0f);
}

extern "C" void kernel_launch(void* const* d_in, const int* in_sizes, int n_in,
                              void* d_out, int out_size, void* d_ws, size_t ws_size,
                              hipStream_t stream) {
    const float* nf = (const float*)d_in[0];
    const int* ei = (const int*)d_in[1];
    const float* Wt = (const float*)d_in[2];
    const float* bt = (const float*)d_in[3];
    const float* Wq = (const float*)d_in[4];
    const float* bq = (const float*)d_in[5];
    const float* Wk = (const float*)d_in[6];
    const float* bk = (const float*)d_in[7];
    const float* Wv = (const float*)d_in[8];
    const float* bv = (const float*)d_in[9];
    const float* hopwise = (const float*)d_in[10];
    const float* headwise = (const float*)d_in[11];
    float* out = (float*)d_out;

    char* p = (char*)d_ws;
    auto alloc = [&](size_t bytes) {
        char* r = p;
        p += (bytes + 255) & ~(size_t)255;
        return r;
    };
    int* rowptr = (int*)alloc((NN + 4) * sizeof(int));
    int* cursor = (int*)alloc((NN + 4) * sizeof(int));
    int* bsum = (int*)alloc(NBLK * sizeof(int));
    int* boff = (int*)alloc(NBLK * sizeof(int));
    int* srows = (int*)alloc((size_t)NE * sizeof(int));
    int* flag = (int*)alloc(sizeof(int));
    ushort* Wtb = (ushort*)alloc(128 * 128 * sizeof(ushort));
    ushort* Wqkvb = (ushort*)alloc(304 * 128 * sizeof(ushort));
    float* Qp = (float*)alloc((size_t)NN * 128 * sizeof(float));      // 25.6 MB
    ushort* Kpp = (ushort*)alloc((size_t)NN * 128 * sizeof(ushort));  // 12.8 MB (K0, later K2)
    ushort* Vbf = (ushort*)alloc((size_t)NN * 64 * sizeof(ushort));   // 6.4 MB
    ushort* Ka = (ushort*)alloc((size_t)NN * 128 * sizeof(ushort));   // 12.8 MB (K1)
    uint4* Mq4a = (uint4*)alloc((size_t)NN * 64 * sizeof(uint4));     // 51.2 MB (fp8 M, c0-7)
    uint4* Mq4b = (uint4*)alloc((size_t)NN * 64 * sizeof(uint4));     // 51.2 MB
    uint* Mrua = (uint*)alloc((size_t)NN * 64 * sizeof(uint));        // 12.8 MB (fp8 M, c8-9)
    uint* Mrub = (uint*)alloc((size_t)NN * 64 * sizeof(uint));        // 12.8 MB
    // total ~189 MB. aliases over dead regions:
    ushort* xb = (ushort*)Mq4a;   // x bf16 (12.8 MB) dead before aggf0 writes Mq4a
    ushort* Kb = Kpp;             // K2 overwrites K0 (K0 last read by aggf0)

    detect_kernel<<<1, 64, 0, stream>>>(ei, flag);
    zero_kernel<<<(NN + 255) / 256, 256, 0, stream>>>(cursor, NN);
    hist_kernel<<<(NE + 255) / 256, 256, 0, stream>>>(ei, flag, cursor);
    bsum_kernel<<<NBLK, 256, 0, stream>>>(cursor, bsum);
    bscan_kernel<<<1, 64, 0, stream>>>(bsum, boff, rowptr);
    scanb_kernel<<<NBLK, 256, 0, stream>>>(cursor, boff, rowptr, cursor);
    scatter_kernel<<<(NE + 255) / 256, 256, 0, stream>>>(ei, flag, cursor, srows);

    wconv_kernel<<<(304 * 128 + 255) / 256, 256, 0, stream>>>(Wt, Wq, Wk, Wv, Wtb, Wqkvb);
    int nrb = (NN + 63) / 64;
    xm_kernel<<<dim3(nrb, 2), 256, 0, stream>>>(nf, Wtb, bt, xb);
    qkv_kernel<<<dim3(nrb, 3), 256, 0, stream>>>(xb, Wqkvb, bq, bk, bv, Qp, Kpp, Vbf);
    vinit_kernel<<<(NN * NC + 255) / 256, 256, 0, stream>>>(out, Vbf, hopwise);

    // hop 0: (K0,V) -> M1/16, K1 ; hop 1: M1 -> M2/16, K2 ; hop 2: M2 -> out only
    aggf0_kernel<<<NN / 4, 256, 0, stream>>>(Kpp, Vbf, Qp, out, Mq4a, Mrua, Ka,
                                             rowptr, srows, hopwise, headwise);
    aggf_kernel<<<NN / 4, 256, 0, stream>>>(Mq4a, Mrua, Ka, Qp, out, Mq4b, Mrub, Kb,
                                            rowptr, srows, hopwise, headwise, 1, 1);
    aggf_kernel<<<NN / 4, 256, 0, stream>>>(Mq4b, Mrub, Kb, Qp, out, Mq4a, Mrua, Ka,
                                            rowptr, srows, hopwise, headwise, 2, 0);
}